// Round 11
// baseline (683.260 us; speedup 1.0000x reference)
//
#include <hip/hip_runtime.h>
#include <hip/hip_bf16.h>

#define EMB 256
#define NHEAD 4
#define HSZ 64
#define NLAYER 3
#define TBLK 2048
#define VOCAB 32000
#define BATCH 4
#define LNEPS 1e-5f
#define BT (BATCH * TBLK)   // 8192 rows
#define QKVD (3 * EMB)      // 768

typedef __attribute__((ext_vector_type(8))) short bf16x8v;  // 8 bf16 (4 VGPRs)
typedef __attribute__((ext_vector_type(4))) float f32x4;
typedef unsigned short u16;
typedef unsigned int u32;

// round-to-nearest-even f32 -> bf16 bits
__device__ __forceinline__ u16 f2bf(float f) {
    union { float f; u32 u; } c; c.f = f;
    u32 r = c.u + 0x7fff + ((c.u >> 16) & 1);
    return (u16)(r >> 16);
}
__device__ __forceinline__ u32 pack2(float a, float b) {
    return (u32)f2bf(a) | ((u32)f2bf(b) << 16);
}

// async global->LDS, 16 bytes per lane (dest linear in lane order)
__device__ __forceinline__ void gload16(const u16* g, u16* l) {
    __builtin_amdgcn_global_load_lds(
        (__attribute__((address_space(1))) void*)g,
        (__attribute__((address_space(3))) void*)l, 16, 0, 0);
}

// ---------------------------------------------------------------------------
// Embedding + fused LN1(layer 0): writes x (fp32) and hb = LN(x) (bf16).
// ---------------------------------------------------------------------------
__global__ __launch_bounds__(256) void embed_ln_kernel(
    const int* __restrict__ idx, const float* __restrict__ tok,
    const float* __restrict__ pos, const float* __restrict__ g,
    const float* __restrict__ b, float* __restrict__ x, u16* __restrict__ hb)
{
    const int row = blockIdx.x * 4 + (threadIdx.x >> 6);
    const int t = row & (TBLK - 1);
    const int token = idx[row];
    const int e = (threadIdx.x & 63) * 4;
    const float4 tv = *(const float4*)&tok[(size_t)token * EMB + e];
    const float4 pv = *(const float4*)&pos[(size_t)t * EMB + e];
    float4 xv;
    xv.x = tv.x + pv.x; xv.y = tv.y + pv.y; xv.z = tv.z + pv.z; xv.w = tv.w + pv.w;
    *(float4*)&x[(size_t)row * EMB + e] = xv;

    float s1 = xv.x + xv.y + xv.z + xv.w;
    float s2 = xv.x * xv.x + xv.y * xv.y + xv.z * xv.z + xv.w * xv.w;
    #pragma unroll
    for (int off = 32; off >= 1; off >>= 1) {
        s1 += __shfl_xor(s1, off);
        s2 += __shfl_xor(s2, off);
    }
    const float mu  = s1 * (1.0f / EMB);
    const float var = s2 * (1.0f / EMB) - mu * mu;
    const float rs  = rsqrtf(var + LNEPS);
    const float4 gv = *(const float4*)&g[e];
    const float4 bv = *(const float4*)&b[e];
    ushort4 o;
    o.x = f2bf((xv.x - mu) * rs * gv.x + bv.x);
    o.y = f2bf((xv.y - mu) * rs * gv.y + bv.y);
    o.z = f2bf((xv.z - mu) * rs * gv.z + bv.z);
    o.w = f2bf((xv.w - mu) * rs * gv.w + bv.w);
    *(ushort4*)&hb[(size_t)row * EMB + e] = o;
}

// ---------------------------------------------------------------------------
// LayerNorm (population var) fp32 in -> bf16 out. 4 rows per block.
// ---------------------------------------------------------------------------
__global__ __launch_bounds__(256) void ln_kernel(
    const float* __restrict__ x, const float* __restrict__ g,
    const float* __restrict__ b, u16* __restrict__ out)
{
    const int row = blockIdx.x * 4 + (threadIdx.x >> 6);
    const int e = (threadIdx.x & 63) * 4;
    const float4 xv = *(const float4*)&x[(size_t)row * EMB + e];
    float s1 = xv.x + xv.y + xv.z + xv.w;
    float s2 = xv.x * xv.x + xv.y * xv.y + xv.z * xv.z + xv.w * xv.w;
    #pragma unroll
    for (int off = 32; off >= 1; off >>= 1) {
        s1 += __shfl_xor(s1, off);
        s2 += __shfl_xor(s2, off);
    }
    const float mu  = s1 * (1.0f / EMB);
    const float var = s2 * (1.0f / EMB) - mu * mu;
    const float rs  = rsqrtf(var + LNEPS);
    const float4 gv = *(const float4*)&g[e];
    const float4 bv = *(const float4*)&b[e];
    ushort4 o;
    o.x = f2bf((xv.x - mu) * rs * gv.x + bv.x);
    o.y = f2bf((xv.y - mu) * rs * gv.y + bv.y);
    o.z = f2bf((xv.z - mu) * rs * gv.z + bv.z);
    o.w = f2bf((xv.w - mu) * rs * gv.w + bv.w);
    *(ushort4*)&out[(size_t)row * EMB + e] = o;
}

// ---------------------------------------------------------------------------
// Transpose + cast: W [K][N] f32 -> Wt [N][K] bf16, batched over layers (z).
// ---------------------------------------------------------------------------
__global__ __launch_bounds__(256) void transpose_cast(
    const float* __restrict__ W, u16* __restrict__ Wt, int K, int N,
    size_t sW, size_t sWt)
{
    __shared__ float t[32][33];
    W  += (size_t)blockIdx.z * sW;
    Wt += (size_t)blockIdx.z * sWt;
    const int bx = blockIdx.x, by = blockIdx.y;
    const int tx = threadIdx.x, ty = threadIdx.y;
    #pragma unroll
    for (int i = 0; i < 32; i += 8)
        t[ty + i][tx] = W[(size_t)(by * 32 + ty + i) * N + bx * 32 + tx];
    __syncthreads();
    #pragma unroll
    for (int i = 0; i < 32; i += 8)
        Wt[(size_t)(bx * 32 + ty + i) * K + by * 32 + tx] = f2bf(t[tx][ty + i]);
}

// Fused ExE transposes: z = layer*4 + {Wq,Wk,Wv,Wproj}
__global__ __launch_bounds__(256) void transpose_qkvp(
    const float* __restrict__ Wq, const float* __restrict__ Wk,
    const float* __restrict__ Wv, const float* __restrict__ Wp,
    u16* __restrict__ Wqkvt, u16* __restrict__ Wprojt)
{
    __shared__ float t[32][33];
    const int which = blockIdx.z & 3, l = blockIdx.z >> 2;
    const float* W;
    u16* Wt;
    switch (which) {
        case 0: W = Wq + (size_t)l*EMB*EMB; Wt = Wqkvt + (size_t)l*QKVD*EMB;               break;
        case 1: W = Wk + (size_t)l*EMB*EMB; Wt = Wqkvt + (size_t)l*QKVD*EMB + EMB*EMB;     break;
        case 2: W = Wv + (size_t)l*EMB*EMB; Wt = Wqkvt + (size_t)l*QKVD*EMB + 2*EMB*EMB;   break;
        default:W = Wp + (size_t)l*EMB*EMB; Wt = Wprojt + (size_t)l*EMB*EMB;               break;
    }
    const int bx = blockIdx.x, by = blockIdx.y;
    const int tx = threadIdx.x, ty = threadIdx.y;
    #pragma unroll
    for (int i = 0; i < 32; i += 8)
        t[ty + i][tx] = W[(size_t)(by * 32 + ty + i) * EMB + bx * 32 + tx];
    __syncthreads();
    #pragma unroll
    for (int i = 0; i < 32; i += 8)
        Wt[(size_t)(bx * 32 + ty + i) * EMB + by * 32 + tx] = f2bf(t[tx][ty + i]);
}

// ---------------------------------------------------------------------------
// MFMA GEMM (R5 version VERBATIM): C = A[M,K] @ Bt[N,K]^T, fp32 accum.
// 128xBNT tile, BK=32, 4 waves. global_load_lds width-16, dbuf, one barrier
// per K-iter. T2 chunk swizzle via pre-swizzled global source + XOR read.
// bm = blockIdx.x (fastest): XCD = bm%8 stable -> A panels pinned in L2.
// ---------------------------------------------------------------------------
template<int BNT, int BIAS, int RES, int RELU, int OUTBF>
__global__ __launch_bounds__(256) void mgemm(
    const u16* __restrict__ A, const u16* __restrict__ Bt,
    const float* __restrict__ bias, const float* __restrict__ res,
    void* __restrict__ Cv, int M, int N, int K)
{
    constexpr int MI = (BNT == 128) ? 4 : 2;
    __shared__ u16 Al[2][128 * 32];
    __shared__ u16 Bl[2][BNT * 32];
    const int tid = threadIdx.x;
    const int bm = blockIdx.x, bn = blockIdx.y;
    const int wid = tid >> 6, lane = tid & 63;
    const int wr = (BNT == 128) ? (wid >> 1) * 64 : wid * 32;
    const int wc = (BNT == 128) ? (wid & 1) * 64 : 0;
    const int fr = lane & 15, fq = lane >> 4;

    // staging: lane covers row wid*16 + lane/4; source chunk pre-swizzled
    const int l4 = lane >> 2;
    const int lc_src = ((lane & 3) ^ ((l4 >> 1) & 3)) * 8;   // global col (swz)
    const u16* Aga = A  + (size_t)(bm * 128 + wid * 16 + l4) * K + lc_src;
    const u16* Bga = Bt + (size_t)(bn * BNT + wid * 16 + l4) * K + lc_src;
    const int lin = (wid * 16 + l4) * 32 + (lane & 3) * 8;   // linear LDS (u16)

    // read-side swizzled chunk offset (per-lane constant)
    const int rsw = (fq ^ ((fr >> 1) & 3)) * 8;

    f32x4 acc[MI][4];
    #pragma unroll
    for (int i = 0; i < MI; ++i)
        #pragma unroll
        for (int j = 0; j < 4; ++j)
            acc[i][j] = f32x4{0.f, 0.f, 0.f, 0.f};

    // prologue: stage K-tile 0 into buf 0
    gload16(Aga,                  &Al[0][lin]);
    gload16(Aga + (size_t)64 * K, &Al[0][lin + 64 * 32]);
    gload16(Bga,                  &Bl[0][lin]);
    if (BNT == 128) gload16(Bga + (size_t)64 * K, &Bl[0][lin + 64 * 32]);

    int buf = 0;
    for (int k0 = 0; k0 < K; k0 += 32, buf ^= 1) {
        __syncthreads();   // vmcnt(0) drain: buf is loaded; prev reads done
        if (k0 + 32 < K) { // async prefetch next tile; hides under MFMA
            gload16(Aga + k0 + 32,                  &Al[buf ^ 1][lin]);
            gload16(Aga + (size_t)64 * K + k0 + 32, &Al[buf ^ 1][lin + 64 * 32]);
            gload16(Bga + k0 + 32,                  &Bl[buf ^ 1][lin]);
            if (BNT == 128)
                gload16(Bga + (size_t)64 * K + k0 + 32, &Bl[buf ^ 1][lin + 64 * 32]);
        }
        bf16x8v af[MI], bfr[4];
        #pragma unroll
        for (int mi = 0; mi < MI; ++mi)
            af[mi] = *(const bf16x8v*)&Al[buf][(wr + mi * 16 + fr) * 32 + rsw];
        #pragma unroll
        for (int ni = 0; ni < 4; ++ni)
            bfr[ni] = *(const bf16x8v*)&Bl[buf][(wc + ni * 16 + fr) * 32 + rsw];
        #pragma unroll
        for (int mi = 0; mi < MI; ++mi)
            #pragma unroll
            for (int ni = 0; ni < 4; ++ni)
                acc[mi][ni] = __builtin_amdgcn_mfma_f32_16x16x32_bf16(
                    af[mi], bfr[ni], acc[mi][ni], 0, 0, 0);
    }

    float* Cf = (float*)Cv;
    u16*   Cb = (u16*)Cv;
    #pragma unroll
    for (int mi = 0; mi < MI; ++mi) {
        #pragma unroll
        for (int j = 0; j < 4; ++j) {
            const int r = bm * 128 + wr + mi * 16 + fq * 4 + j;
            #pragma unroll
            for (int ni = 0; ni < 4; ++ni) {
                const int c = bn * BNT + wc + ni * 16 + fr;
                float v = acc[mi][ni][j];
                if (BIAS) v += bias[c];
                if (RELU) v = fmaxf(v, 0.f);
                if (RES)  v += res[(size_t)r * N + c];
                if (OUTBF) Cb[(size_t)r * N + c] = f2bf(v);
                else       Cf[(size_t)r * N + c] = v;
            }
        }
    }
}

// ---------------------------------------------------------------------------
// Wide-M GEMM for the LM head: 256x128 tile, 512 thr = 8 waves (4 M-groups x
// 2 N-groups, 64x64 each). Same 2-phase dbuf + gload_lds + swizzle as mgemm,
// but 32 MFMA per barrier (2x amortization) and 2x arithmetic intensity.
// Per-XCD: 4 A-panels (512KB) stay L2-resident; B fetched ~once per XCD.
// LDS = 2*(16KB A + 8KB B) = 48KB -> 2 blocks/CU (VGPR-limited).
// ---------------------------------------------------------------------------
template<int BIAS, int OUTBF>
__global__ __launch_bounds__(512) void mgemm_m256(
    const u16* __restrict__ A, const u16* __restrict__ Bt,
    const float* __restrict__ bias, void* __restrict__ Cv, int N, int K)
{
    __shared__ u16 Al[2][256 * 32];   // 16KB each
    __shared__ u16 Bl[2][128 * 32];   // 8KB each
    const int tid = threadIdx.x;
    const int bm = blockIdx.x, bn = blockIdx.y;
    const int wid = tid >> 6, lane = tid & 63;
    const int wr = (wid >> 1) * 64;   // 0/64/128/192
    const int wc = (wid & 1) * 64;    // 0/64
    const int fr = lane & 15, fq = lane >> 4;

    // staging: thread covers row tid>>2 (0..127), chunk tid&3; A needs a
    // second round at rows +128 (same swizzle: ((l4+128)>>1)&3 == (l4>>1)&3).
    const int l4 = tid >> 2;
    const int ch = tid & 3;
    const int lc_src = (ch ^ ((l4 >> 1) & 3)) * 8;   // pre-swizzled source col
    const u16* Aga = A  + (size_t)(bm * 256 + l4) * K + lc_src;
    const u16* Bga = Bt + (size_t)(bn * 128 + l4) * K + lc_src;
    const int lin = l4 * 32 + ch * 8;

    const int rsw = (fq ^ ((fr >> 1) & 3)) * 8;

    f32x4 acc[4][4];
    #pragma unroll
    for (int i = 0; i < 4; ++i)
        #pragma unroll
        for (int j = 0; j < 4; ++j)
            acc[i][j] = f32x4{0.f, 0.f, 0.f, 0.f};

    // prologue
    gload16(Aga,                   &Al[0][lin]);
    gload16(Aga + (size_t)128 * K, &Al[0][lin + 128 * 32]);
    gload16(Bga,                   &Bl[0][lin]);

    int buf = 0;
    for (int k0 = 0; k0 < K; k0 += 32, buf ^= 1) {
        __syncthreads();
        if (k0 + 32 < K) {
            gload16(Aga + k0 + 32,                   &Al[buf ^ 1][lin]);
            gload16(Aga + (size_t)128 * K + k0 + 32, &Al[buf ^ 1][lin + 128 * 32]);
            gload16(Bga + k0 + 32,                   &Bl[buf ^ 1][lin]);
        }
        bf16x8v af[4], bfr[4];
        #pragma unroll
        for (int mi = 0; mi < 4; ++mi)
            af[mi] = *(const bf16x8v*)&Al[buf][(wr + mi * 16 + fr) * 32 + rsw];
        #pragma unroll
        for (int ni = 0; ni < 4; ++ni)
            bfr[ni] = *(const bf16x8v*)&Bl[buf][(wc + ni * 16 + fr) * 32 + rsw];
        #pragma unroll
        for (int mi = 0; mi < 4; ++mi)
            #pragma unroll
            for (int ni = 0; ni < 4; ++ni)
                acc[mi][ni] = __builtin_amdgcn_mfma_f32_16x16x32_bf16(
                    af[mi], bfr[ni], acc[mi][ni], 0, 0, 0);
    }

    float* Cf = (float*)Cv;
    u16*   Cb = (u16*)Cv;
    #pragma unroll
    for (int mi = 0; mi < 4; ++mi) {
        #pragma unroll
        for (int j = 0; j < 4; ++j) {
            const int r = bm * 256 + wr + mi * 16 + fq * 4 + j;
            #pragma unroll
            for (int ni = 0; ni < 4; ++ni) {
                const int c = bn * 128 + wc + ni * 16 + fr;
                float v = acc[mi][ni][j];
                if (BIAS) v += bias[c];
                if (OUTBF) Cb[(size_t)r * N + c] = f2bf(v);
                else       Cf[(size_t)r * N + c] = v;
            }
        }
    }
}

// ---------------------------------------------------------------------------
// MFMA causal flash attention (unchanged from R5).
// ---------------------------------------------------------------------------
__global__ __launch_bounds__(256) void attn_kernel(
    const u16* __restrict__ qkv, u16* __restrict__ y)
{
    constexpr int LDK = 72;
    __shared__ u16 Kl[2][64 * LDK];
    __shared__ u16 Vt[2][64 * LDK];

    const int tid = threadIdx.x;
    const int qt = (int)gridDim.x - 1 - (int)blockIdx.x;
    const int bh = blockIdx.y;
    const int b = bh >> 2, h = bh & 3;
    const int w = tid >> 6, lane = tid & 63;
    const int fr = lane & 15, fq = lane >> 4;
    const size_t rowbase = (size_t)b * TBLK;
    const int qoff = h * HSZ, koff = EMB + h * HSZ, voff = 2 * EMB + h * HSZ;
    const int qg = qt * 64 + w * 16 + fr;

    bf16x8v qf[2];
    #pragma unroll
    for (int ks = 0; ks < 2; ++ks)
        qf[ks] = *(const bf16x8v*)&qkv[(rowbase + qg) * QKVD + qoff + ks * 32 + fq * 8];

    f32x4 yac[4];
    #pragma unroll
    for (int mi = 0; mi < 4; ++mi) yac[mi] = f32x4{0.f, 0.f, 0.f, 0.f};
    float m = -1e30f, l = 0.f;

    const int skv = tid >> 2, sc = (tid & 3) * 16;
    const u16* kbase = &qkv[(rowbase + skv) * QKVD + koff + sc];
    const u16* vbase = &qkv[(rowbase + skv) * QKVD + voff + sc];

    bf16x8v kr0 = *(const bf16x8v*)kbase;
    bf16x8v kr1 = *(const bf16x8v*)(kbase + 8);
    bf16x8v vr0 = *(const bf16x8v*)vbase;
    bf16x8v vr1 = *(const bf16x8v*)(vbase + 8);

    int buf = 0;
    for (int kv0 = 0; kv0 <= qt * 64; kv0 += 64, buf ^= 1) {
        {
            u16* Kw = &Kl[buf][skv * LDK + sc];
            *(bf16x8v*)Kw = kr0; *(bf16x8v*)(Kw + 8) = kr1;
            #pragma unroll
            for (int i = 0; i < 8; ++i) Vt[buf][(sc + i) * LDK + skv] = (u16)vr0[i];
            #pragma unroll
            for (int i = 0; i < 8; ++i) Vt[buf][(sc + 8 + i) * LDK + skv] = (u16)vr1[i];
        }
        __syncthreads();
        if (kv0 + 64 <= qt * 64) {
            const size_t off = (size_t)(kv0 + 64) * QKVD;
            kr0 = *(const bf16x8v*)(kbase + off);
            kr1 = *(const bf16x8v*)(kbase + off + 8);
            vr0 = *(const bf16x8v*)(vbase + off);
            vr1 = *(const bf16x8v*)(vbase + off + 8);
        }

        f32x4 st[4];
        __builtin_amdgcn_s_setprio(1);
        #pragma unroll
        for (int mb = 0; mb < 4; ++mb) {
            st[mb] = f32x4{0.f, 0.f, 0.f, 0.f};
            #pragma unroll
            for (int ks = 0; ks < 2; ++ks) {
                const bf16x8v kf = *(const bf16x8v*)
                    &Kl[buf][(mb * 16 + fr) * LDK + ks * 32 + fq * 8];
                st[mb] = __builtin_amdgcn_mfma_f32_16x16x32_bf16(
                    kf, qf[ks], st[mb], 0, 0, 0);
            }
        }
        __builtin_amdgcn_s_setprio(0);
        float p[4][4];
        float mloc = -1e30f;
        #pragma unroll
        for (int mb = 0; mb < 4; ++mb)
            #pragma unroll
            for (int j = 0; j < 4; ++j) {
                const int kvg = kv0 + mb * 16 + fq * 4 + j;
                const float s = (kvg <= qg) ? st[mb][j] * 0.0625f : -1e30f;
                p[mb][j] = s;
                mloc = fmaxf(mloc, s);
            }
        mloc = fmaxf(mloc, __shfl_xor(mloc, 16));
        mloc = fmaxf(mloc, __shfl_xor(mloc, 32));
        const float mnew = fmaxf(m, mloc);
        const float alpha = __expf(m - mnew);
        float rsum = 0.f;
        #pragma unroll
        for (int mb = 0; mb < 4; ++mb)
            #pragma unroll
            for (int j = 0; j < 4; ++j) {
                p[mb][j] = __expf(p[mb][j] - mnew);
                rsum += p[mb][j];
            }
        rsum += __shfl_xor(rsum, 16);
        rsum += __shfl_xor(rsum, 32);
        l = l * alpha + rsum;
        m = mnew;
        #pragma unroll
        for (int mi = 0; mi < 4; ++mi) yac[mi] *= alpha;

        u32 pk[4][2];
        #pragma unroll
        for (int mb = 0; mb < 4; ++mb) {
            pk[mb][0] = pack2(p[mb][0], p[mb][1]);
            pk[mb][1] = pack2(p[mb][2], p[mb][3]);
        }
        #pragma unroll
        for (int ksv = 0; ksv < 2; ++ksv) {
            union { u32 u[4]; bf16x8v v; } pf;
            #pragma unroll
            for (int t = 0; t < 4; ++t) {
                const int srcl = ((fq & 1) * 2 + (t >> 1)) * 16 + fr;
                const u32 lo = __shfl(pk[ksv * 2 + 0][t & 1], srcl);
                const u32 hi = __shfl(pk[ksv * 2 + 1][t & 1], srcl);
                pf.u[t] = (fq >> 1) ? hi : lo;
            }
            __builtin_amdgcn_s_setprio(1);
            #pragma unroll
            for (int mi = 0; mi < 4; ++mi) {
                const bf16x8v vf = *(const bf16x8v*)
                    &Vt[buf][(mi * 16 + fr) * LDK + ksv * 32 + fq * 8];
                yac[mi] = __builtin_amdgcn_mfma_f32_16x16x32_bf16(
                    vf, pf.v, yac[mi], 0, 0, 0);
            }
            __builtin_amdgcn_s_setprio(0);
        }
    }

    const float inv = 1.f / l;
    #pragma unroll
    for (int mi = 0; mi < 4; ++mi) {
        ushort4 o;
        o.x = f2bf(yac[mi][0] * inv);
        o.y = f2bf(yac[mi][1] * inv);
        o.z = f2bf(yac[mi][2] * inv);
        o.w = f2bf(yac[mi][3] * inv);
        *(ushort4*)&y[(rowbase + qg) * EMB + h * HSZ + mi * 16 + fq * 4] = o;
    }
}

// ---------------------------------------------------------------------------
extern "C" void kernel_launch(void* const* d_in, const int* in_sizes, int n_in,
                              void* d_out, int out_size, void* d_ws, size_t ws_size,
                              hipStream_t stream) {
    const int*   idx   = (const int*)  d_in[0];
    const float* tok   = (const float*)d_in[1];
    const float* pos   = (const float*)d_in[2];
    const float* Wq    = (const float*)d_in[3];
    const float* Wk    = (const float*)d_in[4];
    const float* Wv    = (const float*)d_in[5];
    const float* Wproj = (const float*)d_in[6];
    const float* bproj = (const float*)d_in[7];
    const float* ln1g  = (const float*)d_in[8];
    const float* ln1b  = (const float*)d_in[9];
    const float* W1    = (const float*)d_in[10];
    const float* b1    = (const float*)d_in[11];
    const float* W2    = (const float*)d_in[12];
    const float* b2    = (const float*)d_in[13];
    const float* ln2g  = (const float*)d_in[14];
    const float* ln2b  = (const float*)d_in[15];
    const float* Wlm   = (const float*)d_in[16];
    const float* blm   = (const float*)d_in[17];
    float* out = (float*)d_out;

    float* x    = (float*)d_ws;
    u16*   hb   = (u16*)(x + (size_t)BT * EMB);
    u16*   qkvb = hb + (size_t)BT * EMB;
    u16*   yb   = qkvb + (size_t)BT * QKVD;
    u16*   hid  = qkvb;  // aliases qkv+yb (dead when MLP runs)
    u16*   Wqkvt  = yb + (size_t)BT * EMB;
    u16*   Wprojt = Wqkvt  + (size_t)NLAYER * QKVD * EMB;
    u16*   W1t    = Wprojt + (size_t)NLAYER * EMB * EMB;
    u16*   W2t    = W1t    + (size_t)NLAYER * EMB * 4 * EMB;
    u16*   Wlmt   = W2t    + (size_t)NLAYER * 4 * EMB * EMB;

    const dim3 tb(32, 8);
    transpose_qkvp<<<dim3(8, 8, NLAYER * 4), tb, 0, stream>>>(
        Wq, Wk, Wv, Wproj, Wqkvt, Wprojt);
    transpose_cast<<<dim3(32, 8, NLAYER), tb, 0, stream>>>(
        W1, W1t, EMB, 4*EMB, (size_t)EMB*4*EMB, (size_t)EMB*4*EMB);
    transpose_cast<<<dim3(8, 32, NLAYER), tb, 0, stream>>>(
        W2, W2t, 4*EMB, EMB, (size_t)4*EMB*EMB, (size_t)4*EMB*EMB);
    transpose_cast<<<dim3(VOCAB/32, 8, 1), tb, 0, stream>>>(
        Wlm, Wlmt, EMB, VOCAB, 0, 0);

    embed_ln_kernel<<<BT/4, 256, 0, stream>>>(idx, tok, pos, ln1g, ln1b, x, hb);

    for (int l = 0; l < NLAYER; ++l) {
        mgemm<128,0,0,0,1><<<dim3(BT/128, QKVD/128), 256, 0, stream>>>(
            hb, Wqkvt + (size_t)l*QKVD*EMB, nullptr, nullptr, qkvb, BT, QKVD, EMB);
        attn_kernel<<<dim3(TBLK/64, BATCH*NHEAD), 256, 0, stream>>>(qkvb, yb);
        mgemm<64,1,1,0,0><<<dim3(BT/128, EMB/64), 256, 0, stream>>>(
            yb, Wprojt + (size_t)l*EMB*EMB, bproj + l*EMB, x, x, BT, EMB, EMB);
        ln_kernel<<<BT/4, 256, 0, stream>>>(x, ln2g + l*EMB, ln2b + l*EMB, hb);
        mgemm<128,1,0,1,1><<<dim3(BT/128, 4*EMB/128), 256, 0, stream>>>(
            hb, W1t + (size_t)l*EMB*4*EMB, b1 + l*4*EMB, nullptr, hid, BT, 4*EMB, EMB);
        if (l < NLAYER - 1) {
            mgemm<64,1,1,0,0><<<dim3(BT/128, EMB/64), 256, 0, stream>>>(
                hid, W2t + (size_t)l*4*EMB*EMB, b2 + l*EMB, x, x, BT, EMB, 4*EMB);
            ln_kernel<<<BT/4, 256, 0, stream>>>(
                x, ln1g + (l+1)*EMB, ln1b + (l+1)*EMB, hb);
        } else {
            mgemm<64,1,1,0,1><<<dim3(BT/128, EMB/64), 256, 0, stream>>>(
                hid, W2t + (size_t)l*4*EMB*EMB, b2 + l*EMB, x, hb, BT, EMB, 4*EMB);
        }
    }

    mgemm_m256<1,0><<<dim3(BT/256, VOCAB/128), 512, 0, stream>>>(
        hb, Wlmt, blm, out, VOCAB, EMB);
}

// Round 12
// 635.249 us; speedup vs baseline: 1.0756x; 1.0756x over previous
//
#include <hip/hip_runtime.h>
#include <hip/hip_bf16.h>

#define EMB 256
#define NHEAD 4
#define HSZ 64
#define NLAYER 3
#define TBLK 2048
#define VOCAB 32000
#define BATCH 4
#define LNEPS 1e-5f
#define BT (BATCH * TBLK)   // 8192 rows
#define QKVD (3 * EMB)      // 768

typedef __attribute__((ext_vector_type(8))) short bf16x8v;  // 8 bf16 (4 VGPRs)
typedef __attribute__((ext_vector_type(4))) float f32x4;
typedef unsigned short u16;
typedef unsigned int u32;

// round-to-nearest-even f32 -> bf16 bits
__device__ __forceinline__ u16 f2bf(float f) {
    union { float f; u32 u; } c; c.f = f;
    u32 r = c.u + 0x7fff + ((c.u >> 16) & 1);
    return (u16)(r >> 16);
}
__device__ __forceinline__ u32 pack2(float a, float b) {
    return (u32)f2bf(a) | ((u32)f2bf(b) << 16);
}

// async global->LDS, 16 bytes per lane (dest linear in lane order)
__device__ __forceinline__ void gload16(const u16* g, u16* l) {
    __builtin_amdgcn_global_load_lds(
        (__attribute__((address_space(1))) void*)g,
        (__attribute__((address_space(3))) void*)l, 16, 0, 0);
}

// ---------------------------------------------------------------------------
// Embedding + fused LN1(layer 0): writes x (fp32) and hb = LN(x) (bf16).
// ---------------------------------------------------------------------------
__global__ __launch_bounds__(256) void embed_ln_kernel(
    const int* __restrict__ idx, const float* __restrict__ tok,
    const float* __restrict__ pos, const float* __restrict__ g,
    const float* __restrict__ b, float* __restrict__ x, u16* __restrict__ hb)
{
    const int row = blockIdx.x * 4 + (threadIdx.x >> 6);
    const int t = row & (TBLK - 1);
    const int token = idx[row];
    const int e = (threadIdx.x & 63) * 4;
    const float4 tv = *(const float4*)&tok[(size_t)token * EMB + e];
    const float4 pv = *(const float4*)&pos[(size_t)t * EMB + e];
    float4 xv;
    xv.x = tv.x + pv.x; xv.y = tv.y + pv.y; xv.z = tv.z + pv.z; xv.w = tv.w + pv.w;
    *(float4*)&x[(size_t)row * EMB + e] = xv;

    float s1 = xv.x + xv.y + xv.z + xv.w;
    float s2 = xv.x * xv.x + xv.y * xv.y + xv.z * xv.z + xv.w * xv.w;
    #pragma unroll
    for (int off = 32; off >= 1; off >>= 1) {
        s1 += __shfl_xor(s1, off);
        s2 += __shfl_xor(s2, off);
    }
    const float mu  = s1 * (1.0f / EMB);
    const float var = s2 * (1.0f / EMB) - mu * mu;
    const float rs  = rsqrtf(var + LNEPS);
    const float4 gv = *(const float4*)&g[e];
    const float4 bv = *(const float4*)&b[e];
    ushort4 o;
    o.x = f2bf((xv.x - mu) * rs * gv.x + bv.x);
    o.y = f2bf((xv.y - mu) * rs * gv.y + bv.y);
    o.z = f2bf((xv.z - mu) * rs * gv.z + bv.z);
    o.w = f2bf((xv.w - mu) * rs * gv.w + bv.w);
    *(ushort4*)&hb[(size_t)row * EMB + e] = o;
}

// ---------------------------------------------------------------------------
// LayerNorm (population var) fp32 in -> bf16 out. 4 rows per block.
// ---------------------------------------------------------------------------
__global__ __launch_bounds__(256) void ln_kernel(
    const float* __restrict__ x, const float* __restrict__ g,
    const float* __restrict__ b, u16* __restrict__ out)
{
    const int row = blockIdx.x * 4 + (threadIdx.x >> 6);
    const int e = (threadIdx.x & 63) * 4;
    const float4 xv = *(const float4*)&x[(size_t)row * EMB + e];
    float s1 = xv.x + xv.y + xv.z + xv.w;
    float s2 = xv.x * xv.x + xv.y * xv.y + xv.z * xv.z + xv.w * xv.w;
    #pragma unroll
    for (int off = 32; off >= 1; off >>= 1) {
        s1 += __shfl_xor(s1, off);
        s2 += __shfl_xor(s2, off);
    }
    const float mu  = s1 * (1.0f / EMB);
    const float var = s2 * (1.0f / EMB) - mu * mu;
    const float rs  = rsqrtf(var + LNEPS);
    const float4 gv = *(const float4*)&g[e];
    const float4 bv = *(const float4*)&b[e];
    ushort4 o;
    o.x = f2bf((xv.x - mu) * rs * gv.x + bv.x);
    o.y = f2bf((xv.y - mu) * rs * gv.y + bv.y);
    o.z = f2bf((xv.z - mu) * rs * gv.z + bv.z);
    o.w = f2bf((xv.w - mu) * rs * gv.w + bv.w);
    *(ushort4*)&out[(size_t)row * EMB + e] = o;
}

// ---------------------------------------------------------------------------
// ONE fused transpose+cast dispatch for ALL weights.
// Roles by blockIdx.x range (all 32x32 tiles, block 32x8):
//   [0,768):     Wq/Wk/Wv/Wproj (z=t>>6: l*4+which; r=t&63: bx=r&7, by=r>>3)
//   [768,1536):  W1  [256][1024] -> [1024][256]   (bx=r&31, by=r>>5)
//   [1536,2304): W2  [1024][256] -> [256][1024]   (bx=r&7,  by=r>>3)
//   [2304,10304):Wlm [256][32000] -> [32000][256] (bx=r%1000, by=r/1000)
// ---------------------------------------------------------------------------
__global__ __launch_bounds__(256) void transpose_all(
    const float* __restrict__ Wq, const float* __restrict__ Wk,
    const float* __restrict__ Wv, const float* __restrict__ Wp,
    const float* __restrict__ W1, const float* __restrict__ W2,
    const float* __restrict__ Wlm,
    u16* __restrict__ Wqkvt, u16* __restrict__ Wprojt, u16* __restrict__ W1t,
    u16* __restrict__ W2t, u16* __restrict__ Wlmt)
{
    __shared__ float t[32][33];
    const int tb = blockIdx.x;
    const float* W;
    u16* Wt;
    int K, N, bx, by;
    if (tb < 768) {
        const int z = tb >> 6, r = tb & 63;
        const int which = z & 3, l = z >> 2;
        switch (which) {
            case 0: W = Wq + (size_t)l*EMB*EMB; Wt = Wqkvt + (size_t)l*QKVD*EMB;             break;
            case 1: W = Wk + (size_t)l*EMB*EMB; Wt = Wqkvt + (size_t)l*QKVD*EMB + EMB*EMB;   break;
            case 2: W = Wv + (size_t)l*EMB*EMB; Wt = Wqkvt + (size_t)l*QKVD*EMB + 2*EMB*EMB; break;
            default:W = Wp + (size_t)l*EMB*EMB; Wt = Wprojt + (size_t)l*EMB*EMB;             break;
        }
        K = EMB; N = EMB; bx = r & 7; by = r >> 3;
    } else if (tb < 1536) {
        const int t2 = tb - 768, l = t2 >> 8, r = t2 & 255;
        W = W1 + (size_t)l*EMB*4*EMB; Wt = W1t + (size_t)l*EMB*4*EMB;
        K = EMB; N = 4*EMB; bx = r & 31; by = r >> 5;
    } else if (tb < 2304) {
        const int t2 = tb - 1536, l = t2 >> 8, r = t2 & 255;
        W = W2 + (size_t)l*4*EMB*EMB; Wt = W2t + (size_t)l*4*EMB*EMB;
        K = 4*EMB; N = EMB; bx = r & 7; by = r >> 3;
    } else {
        const int r = tb - 2304;
        W = Wlm; Wt = Wlmt;
        K = EMB; N = VOCAB; bx = r % 1000; by = r / 1000;
    }
    const int tx = threadIdx.x, ty = threadIdx.y;
    #pragma unroll
    for (int i = 0; i < 32; i += 8)
        t[ty + i][tx] = W[(size_t)(by * 32 + ty + i) * N + bx * 32 + tx];
    __syncthreads();
    #pragma unroll
    for (int i = 0; i < 32; i += 8)
        Wt[(size_t)(bx * 32 + ty + i) * K + by * 32 + tx] = f2bf(t[tx][ty + i]);
}

// ---------------------------------------------------------------------------
// MFMA GEMM (R5 version VERBATIM): C = A[M,K] @ Bt[N,K]^T, fp32 accum.
// 128xBNT tile, BK=32, 4 waves. global_load_lds width-16, dbuf, one barrier
// per K-iter. T2 chunk swizzle via pre-swizzled global source + XOR read.
// bm = blockIdx.x (fastest): XCD = bm%8 stable -> A panels pinned in L2.
// BNT=64 for small-N ops (B fully L2-resident; 2x blocks/CU hides barrier).
// ---------------------------------------------------------------------------
template<int BNT, int BIAS, int RES, int RELU, int OUTBF>
__global__ __launch_bounds__(256) void mgemm(
    const u16* __restrict__ A, const u16* __restrict__ Bt,
    const float* __restrict__ bias, const float* __restrict__ res,
    void* __restrict__ Cv, int M, int N, int K)
{
    constexpr int MI = (BNT == 128) ? 4 : 2;
    __shared__ u16 Al[2][128 * 32];
    __shared__ u16 Bl[2][BNT * 32];
    const int tid = threadIdx.x;
    const int bm = blockIdx.x, bn = blockIdx.y;
    const int wid = tid >> 6, lane = tid & 63;
    const int wr = (BNT == 128) ? (wid >> 1) * 64 : wid * 32;
    const int wc = (BNT == 128) ? (wid & 1) * 64 : 0;
    const int fr = lane & 15, fq = lane >> 4;

    // staging: lane covers row wid*16 + lane/4; source chunk pre-swizzled
    const int l4 = lane >> 2;
    const int lc_src = ((lane & 3) ^ ((l4 >> 1) & 3)) * 8;   // global col (swz)
    const u16* Aga = A  + (size_t)(bm * 128 + wid * 16 + l4) * K + lc_src;
    const u16* Bga = Bt + (size_t)(bn * BNT + wid * 16 + l4) * K + lc_src;
    const int lin = (wid * 16 + l4) * 32 + (lane & 3) * 8;   // linear LDS (u16)

    // read-side swizzled chunk offset (per-lane constant)
    const int rsw = (fq ^ ((fr >> 1) & 3)) * 8;

    f32x4 acc[MI][4];
    #pragma unroll
    for (int i = 0; i < MI; ++i)
        #pragma unroll
        for (int j = 0; j < 4; ++j)
            acc[i][j] = f32x4{0.f, 0.f, 0.f, 0.f};

    // prologue: stage K-tile 0 into buf 0
    gload16(Aga,                  &Al[0][lin]);
    gload16(Aga + (size_t)64 * K, &Al[0][lin + 64 * 32]);
    gload16(Bga,                  &Bl[0][lin]);
    if (BNT == 128) gload16(Bga + (size_t)64 * K, &Bl[0][lin + 64 * 32]);

    int buf = 0;
    for (int k0 = 0; k0 < K; k0 += 32, buf ^= 1) {
        __syncthreads();   // vmcnt(0) drain: buf is loaded; prev reads done
        if (k0 + 32 < K) { // async prefetch next tile; hides under MFMA
            gload16(Aga + k0 + 32,                  &Al[buf ^ 1][lin]);
            gload16(Aga + (size_t)64 * K + k0 + 32, &Al[buf ^ 1][lin + 64 * 32]);
            gload16(Bga + k0 + 32,                  &Bl[buf ^ 1][lin]);
            if (BNT == 128)
                gload16(Bga + (size_t)64 * K + k0 + 32, &Bl[buf ^ 1][lin + 64 * 32]);
        }
        bf16x8v af[MI], bfr[4];
        #pragma unroll
        for (int mi = 0; mi < MI; ++mi)
            af[mi] = *(const bf16x8v*)&Al[buf][(wr + mi * 16 + fr) * 32 + rsw];
        #pragma unroll
        for (int ni = 0; ni < 4; ++ni)
            bfr[ni] = *(const bf16x8v*)&Bl[buf][(wc + ni * 16 + fr) * 32 + rsw];
        #pragma unroll
        for (int mi = 0; mi < MI; ++mi)
            #pragma unroll
            for (int ni = 0; ni < 4; ++ni)
                acc[mi][ni] = __builtin_amdgcn_mfma_f32_16x16x32_bf16(
                    af[mi], bfr[ni], acc[mi][ni], 0, 0, 0);
    }

    float* Cf = (float*)Cv;
    u16*   Cb = (u16*)Cv;
    #pragma unroll
    for (int mi = 0; mi < MI; ++mi) {
        #pragma unroll
        for (int j = 0; j < 4; ++j) {
            const int r = bm * 128 + wr + mi * 16 + fq * 4 + j;
            #pragma unroll
            for (int ni = 0; ni < 4; ++ni) {
                const int c = bn * BNT + wc + ni * 16 + fr;
                float v = acc[mi][ni][j];
                if (BIAS) v += bias[c];
                if (RELU) v = fmaxf(v, 0.f);
                if (RES)  v += res[(size_t)r * N + c];
                if (OUTBF) Cb[(size_t)r * N + c] = f2bf(v);
                else       Cf[(size_t)r * N + c] = v;
            }
        }
    }
}

// ---------------------------------------------------------------------------
// Wide-M GEMM for the LM head: 256x128 tile, 512 thr = 8 waves (4Mx2N of
// 64x64). 2-phase dbuf + gload_lds + swizzle. Epilogue uses NON-TEMPORAL
// stores: the 1 GB fp32 logits stream is never re-read -- bypassing L2 keeps
// the B panels resident instead of being evicted by the write stream.
// ---------------------------------------------------------------------------
template<int BIAS>
__global__ __launch_bounds__(512) void mgemm_m256(
    const u16* __restrict__ A, const u16* __restrict__ Bt,
    const float* __restrict__ bias, float* __restrict__ Cf, int N, int K)
{
    __shared__ u16 Al[2][256 * 32];   // 16KB each
    __shared__ u16 Bl[2][128 * 32];   // 8KB each
    const int tid = threadIdx.x;
    const int bm = blockIdx.x, bn = blockIdx.y;
    const int wid = tid >> 6, lane = tid & 63;
    const int wr = (wid >> 1) * 64;   // 0/64/128/192
    const int wc = (wid & 1) * 64;    // 0/64
    const int fr = lane & 15, fq = lane >> 4;

    const int l4 = tid >> 2;
    const int ch = tid & 3;
    const int lc_src = (ch ^ ((l4 >> 1) & 3)) * 8;   // pre-swizzled source col
    const u16* Aga = A  + (size_t)(bm * 256 + l4) * K + lc_src;
    const u16* Bga = Bt + (size_t)(bn * 128 + l4) * K + lc_src;
    const int lin = l4 * 32 + ch * 8;

    const int rsw = (fq ^ ((fr >> 1) & 3)) * 8;

    f32x4 acc[4][4];
    #pragma unroll
    for (int i = 0; i < 4; ++i)
        #pragma unroll
        for (int j = 0; j < 4; ++j)
            acc[i][j] = f32x4{0.f, 0.f, 0.f, 0.f};

    // prologue
    gload16(Aga,                   &Al[0][lin]);
    gload16(Aga + (size_t)128 * K, &Al[0][lin + 128 * 32]);
    gload16(Bga,                   &Bl[0][lin]);

    int buf = 0;
    for (int k0 = 0; k0 < K; k0 += 32, buf ^= 1) {
        __syncthreads();
        if (k0 + 32 < K) {
            gload16(Aga + k0 + 32,                   &Al[buf ^ 1][lin]);
            gload16(Aga + (size_t)128 * K + k0 + 32, &Al[buf ^ 1][lin + 128 * 32]);
            gload16(Bga + k0 + 32,                   &Bl[buf ^ 1][lin]);
        }
        bf16x8v af[4], bfr[4];
        #pragma unroll
        for (int mi = 0; mi < 4; ++mi)
            af[mi] = *(const bf16x8v*)&Al[buf][(wr + mi * 16 + fr) * 32 + rsw];
        #pragma unroll
        for (int ni = 0; ni < 4; ++ni)
            bfr[ni] = *(const bf16x8v*)&Bl[buf][(wc + ni * 16 + fr) * 32 + rsw];
        #pragma unroll
        for (int mi = 0; mi < 4; ++mi)
            #pragma unroll
            for (int ni = 0; ni < 4; ++ni)
                acc[mi][ni] = __builtin_amdgcn_mfma_f32_16x16x32_bf16(
                    af[mi], bfr[ni], acc[mi][ni], 0, 0, 0);
    }

    #pragma unroll
    for (int mi = 0; mi < 4; ++mi) {
        #pragma unroll
        for (int j = 0; j < 4; ++j) {
            const int r = bm * 256 + wr + mi * 16 + fq * 4 + j;
            #pragma unroll
            for (int ni = 0; ni < 4; ++ni) {
                const int c = bn * 128 + wc + ni * 16 + fr;
                float v = acc[mi][ni][j];
                if (BIAS) v += bias[c];
                __builtin_nontemporal_store(v, &Cf[(size_t)r * N + c]);
            }
        }
    }
}

// ---------------------------------------------------------------------------
// MFMA causal flash attention (unchanged from R5).
// ---------------------------------------------------------------------------
__global__ __launch_bounds__(256) void attn_kernel(
    const u16* __restrict__ qkv, u16* __restrict__ y)
{
    constexpr int LDK = 72;
    __shared__ u16 Kl[2][64 * LDK];
    __shared__ u16 Vt[2][64 * LDK];

    const int tid = threadIdx.x;
    const int qt = (int)gridDim.x - 1 - (int)blockIdx.x;
    const int bh = blockIdx.y;
    const int b = bh >> 2, h = bh & 3;
    const int w = tid >> 6, lane = tid & 63;
    const int fr = lane & 15, fq = lane >> 4;
    const size_t rowbase = (size_t)b * TBLK;
    const int qoff = h * HSZ, koff = EMB + h * HSZ, voff = 2 * EMB + h * HSZ;
    const int qg = qt * 64 + w * 16 + fr;

    bf16x8v qf[2];
    #pragma unroll
    for (int ks = 0; ks < 2; ++ks)
        qf[ks] = *(const bf16x8v*)&qkv[(rowbase + qg) * QKVD + qoff + ks * 32 + fq * 8];

    f32x4 yac[4];
    #pragma unroll
    for (int mi = 0; mi < 4; ++mi) yac[mi] = f32x4{0.f, 0.f, 0.f, 0.f};
    float m = -1e30f, l = 0.f;

    const int skv = tid >> 2, sc = (tid & 3) * 16;
    const u16* kbase = &qkv[(rowbase + skv) * QKVD + koff + sc];
    const u16* vbase = &qkv[(rowbase + skv) * QKVD + voff + sc];

    bf16x8v kr0 = *(const bf16x8v*)kbase;
    bf16x8v kr1 = *(const bf16x8v*)(kbase + 8);
    bf16x8v vr0 = *(const bf16x8v*)vbase;
    bf16x8v vr1 = *(const bf16x8v*)(vbase + 8);

    int buf = 0;
    for (int kv0 = 0; kv0 <= qt * 64; kv0 += 64, buf ^= 1) {
        {
            u16* Kw = &Kl[buf][skv * LDK + sc];
            *(bf16x8v*)Kw = kr0; *(bf16x8v*)(Kw + 8) = kr1;
            #pragma unroll
            for (int i = 0; i < 8; ++i) Vt[buf][(sc + i) * LDK + skv] = (u16)vr0[i];
            #pragma unroll
            for (int i = 0; i < 8; ++i) Vt[buf][(sc + 8 + i) * LDK + skv] = (u16)vr1[i];
        }
        __syncthreads();
        if (kv0 + 64 <= qt * 64) {
            const size_t off = (size_t)(kv0 + 64) * QKVD;
            kr0 = *(const bf16x8v*)(kbase + off);
            kr1 = *(const bf16x8v*)(kbase + off + 8);
            vr0 = *(const bf16x8v*)(vbase + off);
            vr1 = *(const bf16x8v*)(vbase + off + 8);
        }

        f32x4 st[4];
        __builtin_amdgcn_s_setprio(1);
        #pragma unroll
        for (int mb = 0; mb < 4; ++mb) {
            st[mb] = f32x4{0.f, 0.f, 0.f, 0.f};
            #pragma unroll
            for (int ks = 0; ks < 2; ++ks) {
                const bf16x8v kf = *(const bf16x8v*)
                    &Kl[buf][(mb * 16 + fr) * LDK + ks * 32 + fq * 8];
                st[mb] = __builtin_amdgcn_mfma_f32_16x16x32_bf16(
                    kf, qf[ks], st[mb], 0, 0, 0);
            }
        }
        __builtin_amdgcn_s_setprio(0);
        float p[4][4];
        float mloc = -1e30f;
        #pragma unroll
        for (int mb = 0; mb < 4; ++mb)
            #pragma unroll
            for (int j = 0; j < 4; ++j) {
                const int kvg = kv0 + mb * 16 + fq * 4 + j;
                const float s = (kvg <= qg) ? st[mb][j] * 0.0625f : -1e30f;
                p[mb][j] = s;
                mloc = fmaxf(mloc, s);
            }
        mloc = fmaxf(mloc, __shfl_xor(mloc, 16));
        mloc = fmaxf(mloc, __shfl_xor(mloc, 32));
        const float mnew = fmaxf(m, mloc);
        const float alpha = __expf(m - mnew);
        float rsum = 0.f;
        #pragma unroll
        for (int mb = 0; mb < 4; ++mb)
            #pragma unroll
            for (int j = 0; j < 4; ++j) {
                p[mb][j] = __expf(p[mb][j] - mnew);
                rsum += p[mb][j];
            }
        rsum += __shfl_xor(rsum, 16);
        rsum += __shfl_xor(rsum, 32);
        l = l * alpha + rsum;
        m = mnew;
        #pragma unroll
        for (int mi = 0; mi < 4; ++mi) yac[mi] *= alpha;

        u32 pk[4][2];
        #pragma unroll
        for (int mb = 0; mb < 4; ++mb) {
            pk[mb][0] = pack2(p[mb][0], p[mb][1]);
            pk[mb][1] = pack2(p[mb][2], p[mb][3]);
        }
        #pragma unroll
        for (int ksv = 0; ksv < 2; ++ksv) {
            union { u32 u[4]; bf16x8v v; } pf;
            #pragma unroll
            for (int t = 0; t < 4; ++t) {
                const int srcl = ((fq & 1) * 2 + (t >> 1)) * 16 + fr;
                const u32 lo = __shfl(pk[ksv * 2 + 0][t & 1], srcl);
                const u32 hi = __shfl(pk[ksv * 2 + 1][t & 1], srcl);
                pf.u[t] = (fq >> 1) ? hi : lo;
            }
            __builtin_amdgcn_s_setprio(1);
            #pragma unroll
            for (int mi = 0; mi < 4; ++mi) {
                const bf16x8v vf = *(const bf16x8v*)
                    &Vt[buf][(mi * 16 + fr) * LDK + ksv * 32 + fq * 8];
                yac[mi] = __builtin_amdgcn_mfma_f32_16x16x32_bf16(
                    vf, pf.v, yac[mi], 0, 0, 0);
            }
            __builtin_amdgcn_s_setprio(0);
        }
    }

    const float inv = 1.f / l;
    #pragma unroll
    for (int mi = 0; mi < 4; ++mi) {
        ushort4 o;
        o.x = f2bf(yac[mi][0] * inv);
        o.y = f2bf(yac[mi][1] * inv);
        o.z = f2bf(yac[mi][2] * inv);
        o.w = f2bf(yac[mi][3] * inv);
        *(ushort4*)&y[(rowbase + qg) * EMB + h * HSZ + mi * 16 + fq * 4] = o;
    }
}

// ---------------------------------------------------------------------------
extern "C" void kernel_launch(void* const* d_in, const int* in_sizes, int n_in,
                              void* d_out, int out_size, void* d_ws, size_t ws_size,
                              hipStream_t stream) {
    const int*   idx   = (const int*)  d_in[0];
    const float* tok   = (const float*)d_in[1];
    const float* pos   = (const float*)d_in[2];
    const float* Wq    = (const float*)d_in[3];
    const float* Wk    = (const float*)d_in[4];
    const float* Wv    = (const float*)d_in[5];
    const float* Wproj = (const float*)d_in[6];
    const float* bproj = (const float*)d_in[7];
    const float* ln1g  = (const float*)d_in[8];
    const float* ln1b  = (const float*)d_in[9];
    const float* W1    = (const float*)d_in[10];
    const float* b1    = (const float*)d_in[11];
    const float* W2    = (const float*)d_in[12];
    const float* b2    = (const float*)d_in[13];
    const float* ln2g  = (const float*)d_in[14];
    const float* ln2b  = (const float*)d_in[15];
    const float* Wlm   = (const float*)d_in[16];
    const float* blm   = (const float*)d_in[17];
    float* out = (float*)d_out;

    float* x    = (float*)d_ws;
    u16*   hb   = (u16*)(x + (size_t)BT * EMB);
    u16*   qkvb = hb + (size_t)BT * EMB;
    u16*   yb   = qkvb + (size_t)BT * QKVD;
    u16*   hid  = qkvb;  // aliases qkv+yb (dead when MLP runs)
    u16*   Wqkvt  = yb + (size_t)BT * EMB;
    u16*   Wprojt = Wqkvt  + (size_t)NLAYER * QKVD * EMB;
    u16*   W1t    = Wprojt + (size_t)NLAYER * EMB * EMB;
    u16*   W2t    = W1t    + (size_t)NLAYER * EMB * 4 * EMB;
    u16*   Wlmt   = W2t    + (size_t)NLAYER * 4 * EMB * EMB;

    transpose_all<<<2304 + (VOCAB/32)*8, dim3(32, 8), 0, stream>>>(
        Wq, Wk, Wv, Wproj, W1, W2, Wlm, Wqkvt, Wprojt, W1t, W2t, Wlmt);

    embed_ln_kernel<<<BT/4, 256, 0, stream>>>(idx, tok, pos, ln1g, ln1b, x, hb);

    for (int l = 0; l < NLAYER; ++l) {
        mgemm<64,0,0,0,1><<<dim3(BT/128, QKVD/64), 256, 0, stream>>>(
            hb, Wqkvt + (size_t)l*QKVD*EMB, nullptr, nullptr, qkvb, BT, QKVD, EMB);
        attn_kernel<<<dim3(TBLK/64, BATCH*NHEAD), 256, 0, stream>>>(qkvb, yb);
        mgemm<64,1,1,0,0><<<dim3(BT/128, EMB/64), 256, 0, stream>>>(
            yb, Wprojt + (size_t)l*EMB*EMB, bproj + l*EMB, x, x, BT, EMB, EMB);
        ln_kernel<<<BT/4, 256, 0, stream>>>(x, ln2g + l*EMB, ln2b + l*EMB, hb);
        mgemm<64,1,0,1,1><<<dim3(BT/128, 4*EMB/64), 256, 0, stream>>>(
            hb, W1t + (size_t)l*EMB*4*EMB, b1 + l*4*EMB, nullptr, hid, BT, 4*EMB, EMB);
        if (l < NLAYER - 1) {
            mgemm<64,1,1,0,0><<<dim3(BT/128, EMB/64), 256, 0, stream>>>(
                hid, W2t + (size_t)l*4*EMB*EMB, b2 + l*EMB, x, x, BT, EMB, 4*EMB);
            ln_kernel<<<BT/4, 256, 0, stream>>>(
                x, ln1g + (l+1)*EMB, ln1b + (l+1)*EMB, hb);
        } else {
            mgemm<64,1,1,0,1><<<dim3(BT/128, EMB/64), 256, 0, stream>>>(
                hid, W2t + (size_t)l*4*EMB*EMB, b2 + l*EMB, x, hb, BT, EMB, 4*EMB);
        }
    }

    mgemm_m256<1><<<dim3(BT/256, VOCAB/128), 512, 0, stream>>>(
        hb, Wlmt, blm, out, VOCAB, EMB);
}

// Round 13
// 616.956 us; speedup vs baseline: 1.1075x; 1.0297x over previous
//
#include <hip/hip_runtime.h>
#include <hip/hip_bf16.h>

#define EMB 256
#define NHEAD 4
#define HSZ 64
#define NLAYER 3
#define TBLK 2048
#define VOCAB 32000
#define BATCH 4
#define LNEPS 1e-5f
#define BT (BATCH * TBLK)   // 8192 rows
#define QKVD (3 * EMB)      // 768

typedef __attribute__((ext_vector_type(8))) short bf16x8v;  // 8 bf16 (4 VGPRs)
typedef __attribute__((ext_vector_type(4))) float f32x4;
typedef unsigned short u16;
typedef unsigned int u32;

// round-to-nearest-even f32 -> bf16 bits
__device__ __forceinline__ u16 f2bf(float f) {
    union { float f; u32 u; } c; c.f = f;
    u32 r = c.u + 0x7fff + ((c.u >> 16) & 1);
    return (u16)(r >> 16);
}
__device__ __forceinline__ u32 pack2(float a, float b) {
    return (u32)f2bf(a) | ((u32)f2bf(b) << 16);
}

// async global->LDS, 16 bytes per lane (dest linear in lane order)
__device__ __forceinline__ void gload16(const u16* g, u16* l) {
    __builtin_amdgcn_global_load_lds(
        (__attribute__((address_space(1))) void*)g,
        (__attribute__((address_space(3))) void*)l, 16, 0, 0);
}

// ---------------------------------------------------------------------------
// Embedding + fused LN1(layer 0): writes x (fp32) and hb = LN(x) (bf16).
// ---------------------------------------------------------------------------
__global__ __launch_bounds__(256) void embed_ln_kernel(
    const int* __restrict__ idx, const float* __restrict__ tok,
    const float* __restrict__ pos, const float* __restrict__ g,
    const float* __restrict__ b, float* __restrict__ x, u16* __restrict__ hb)
{
    const int row = blockIdx.x * 4 + (threadIdx.x >> 6);
    const int t = row & (TBLK - 1);
    const int token = idx[row];
    const int e = (threadIdx.x & 63) * 4;
    const float4 tv = *(const float4*)&tok[(size_t)token * EMB + e];
    const float4 pv = *(const float4*)&pos[(size_t)t * EMB + e];
    float4 xv;
    xv.x = tv.x + pv.x; xv.y = tv.y + pv.y; xv.z = tv.z + pv.z; xv.w = tv.w + pv.w;
    *(float4*)&x[(size_t)row * EMB + e] = xv;

    float s1 = xv.x + xv.y + xv.z + xv.w;
    float s2 = xv.x * xv.x + xv.y * xv.y + xv.z * xv.z + xv.w * xv.w;
    #pragma unroll
    for (int off = 32; off >= 1; off >>= 1) {
        s1 += __shfl_xor(s1, off);
        s2 += __shfl_xor(s2, off);
    }
    const float mu  = s1 * (1.0f / EMB);
    const float var = s2 * (1.0f / EMB) - mu * mu;
    const float rs  = rsqrtf(var + LNEPS);
    const float4 gv = *(const float4*)&g[e];
    const float4 bv = *(const float4*)&b[e];
    ushort4 o;
    o.x = f2bf((xv.x - mu) * rs * gv.x + bv.x);
    o.y = f2bf((xv.y - mu) * rs * gv.y + bv.y);
    o.z = f2bf((xv.z - mu) * rs * gv.z + bv.z);
    o.w = f2bf((xv.w - mu) * rs * gv.w + bv.w);
    *(ushort4*)&hb[(size_t)row * EMB + e] = o;
}

// ---------------------------------------------------------------------------
// LayerNorm (population var) fp32 in -> bf16 out. 4 rows per block.
// ---------------------------------------------------------------------------
__global__ __launch_bounds__(256) void ln_kernel(
    const float* __restrict__ x, const float* __restrict__ g,
    const float* __restrict__ b, u16* __restrict__ out)
{
    const int row = blockIdx.x * 4 + (threadIdx.x >> 6);
    const int e = (threadIdx.x & 63) * 4;
    const float4 xv = *(const float4*)&x[(size_t)row * EMB + e];
    float s1 = xv.x + xv.y + xv.z + xv.w;
    float s2 = xv.x * xv.x + xv.y * xv.y + xv.z * xv.z + xv.w * xv.w;
    #pragma unroll
    for (int off = 32; off >= 1; off >>= 1) {
        s1 += __shfl_xor(s1, off);
        s2 += __shfl_xor(s2, off);
    }
    const float mu  = s1 * (1.0f / EMB);
    const float var = s2 * (1.0f / EMB) - mu * mu;
    const float rs  = rsqrtf(var + LNEPS);
    const float4 gv = *(const float4*)&g[e];
    const float4 bv = *(const float4*)&b[e];
    ushort4 o;
    o.x = f2bf((xv.x - mu) * rs * gv.x + bv.x);
    o.y = f2bf((xv.y - mu) * rs * gv.y + bv.y);
    o.z = f2bf((xv.z - mu) * rs * gv.z + bv.z);
    o.w = f2bf((xv.w - mu) * rs * gv.w + bv.w);
    *(ushort4*)&out[(size_t)row * EMB + e] = o;
}

// ---------------------------------------------------------------------------
// ONE fused transpose+cast dispatch for ALL weights (R11, unchanged).
// ---------------------------------------------------------------------------
__global__ __launch_bounds__(256) void transpose_all(
    const float* __restrict__ Wq, const float* __restrict__ Wk,
    const float* __restrict__ Wv, const float* __restrict__ Wp,
    const float* __restrict__ W1, const float* __restrict__ W2,
    const float* __restrict__ Wlm,
    u16* __restrict__ Wqkvt, u16* __restrict__ Wprojt, u16* __restrict__ W1t,
    u16* __restrict__ W2t, u16* __restrict__ Wlmt)
{
    __shared__ float t[32][33];
    const int tb = blockIdx.x;
    const float* W;
    u16* Wt;
    int K, N, bx, by;
    if (tb < 768) {
        const int z = tb >> 6, r = tb & 63;
        const int which = z & 3, l = z >> 2;
        switch (which) {
            case 0: W = Wq + (size_t)l*EMB*EMB; Wt = Wqkvt + (size_t)l*QKVD*EMB;             break;
            case 1: W = Wk + (size_t)l*EMB*EMB; Wt = Wqkvt + (size_t)l*QKVD*EMB + EMB*EMB;   break;
            case 2: W = Wv + (size_t)l*EMB*EMB; Wt = Wqkvt + (size_t)l*QKVD*EMB + 2*EMB*EMB; break;
            default:W = Wp + (size_t)l*EMB*EMB; Wt = Wprojt + (size_t)l*EMB*EMB;             break;
        }
        K = EMB; N = EMB; bx = r & 7; by = r >> 3;
    } else if (tb < 1536) {
        const int t2 = tb - 768, l = t2 >> 8, r = t2 & 255;
        W = W1 + (size_t)l*EMB*4*EMB; Wt = W1t + (size_t)l*EMB*4*EMB;
        K = EMB; N = 4*EMB; bx = r & 31; by = r >> 5;
    } else if (tb < 2304) {
        const int t2 = tb - 1536, l = t2 >> 8, r = t2 & 255;
        W = W2 + (size_t)l*4*EMB*EMB; Wt = W2t + (size_t)l*4*EMB*EMB;
        K = 4*EMB; N = EMB; bx = r & 7; by = r >> 3;
    } else {
        const int r = tb - 2304;
        W = Wlm; Wt = Wlmt;
        K = EMB; N = VOCAB; bx = r % 1000; by = r / 1000;
    }
    const int tx = threadIdx.x, ty = threadIdx.y;
    #pragma unroll
    for (int i = 0; i < 32; i += 8)
        t[ty + i][tx] = W[(size_t)(by * 32 + ty + i) * N + bx * 32 + tx];
    __syncthreads();
    #pragma unroll
    for (int i = 0; i < 32; i += 8)
        Wt[(size_t)(bx * 32 + ty + i) * K + by * 32 + tx] = f2bf(t[tx][ty + i]);
}

// ---------------------------------------------------------------------------
// MFMA GEMM (R5 structure): C = A[M,K] @ Bt[N,K]^T, fp32 accum.
// 128xBNT tile, BK=32, 4 waves. global_load_lds + dbuf + 1 barrier/K-iter.
// T2 chunk swizzle via pre-swizzled global source + XOR read.
// ---------------------------------------------------------------------------
template<int BNT, int BIAS, int RES, int RELU, int OUTBF>
__global__ __launch_bounds__(256) void mgemm(
    const u16* __restrict__ A, const u16* __restrict__ Bt,
    const float* __restrict__ bias, const float* __restrict__ res,
    void* __restrict__ Cv, int M, int N, int K)
{
    constexpr int MI = (BNT == 128) ? 4 : 2;
    __shared__ u16 Al[2][128 * 32];
    __shared__ u16 Bl[2][BNT * 32];
    const int tid = threadIdx.x;
    const int bm = blockIdx.x, bn = blockIdx.y;
    const int wid = tid >> 6, lane = tid & 63;
    const int wr = (BNT == 128) ? (wid >> 1) * 64 : wid * 32;
    const int wc = (BNT == 128) ? (wid & 1) * 64 : 0;
    const int fr = lane & 15, fq = lane >> 4;

    const int l4 = lane >> 2;
    const int lc_src = ((lane & 3) ^ ((l4 >> 1) & 3)) * 8;   // global col (swz)
    const u16* Aga = A  + (size_t)(bm * 128 + wid * 16 + l4) * K + lc_src;
    const u16* Bga = Bt + (size_t)(bn * BNT + wid * 16 + l4) * K + lc_src;
    const int lin = (wid * 16 + l4) * 32 + (lane & 3) * 8;   // linear LDS (u16)

    const int rsw = (fq ^ ((fr >> 1) & 3)) * 8;

    f32x4 acc[MI][4];
    #pragma unroll
    for (int i = 0; i < MI; ++i)
        #pragma unroll
        for (int j = 0; j < 4; ++j)
            acc[i][j] = f32x4{0.f, 0.f, 0.f, 0.f};

    gload16(Aga,                  &Al[0][lin]);
    gload16(Aga + (size_t)64 * K, &Al[0][lin + 64 * 32]);
    gload16(Bga,                  &Bl[0][lin]);
    if (BNT == 128) gload16(Bga + (size_t)64 * K, &Bl[0][lin + 64 * 32]);

    int buf = 0;
    for (int k0 = 0; k0 < K; k0 += 32, buf ^= 1) {
        __syncthreads();
        if (k0 + 32 < K) {
            gload16(Aga + k0 + 32,                  &Al[buf ^ 1][lin]);
            gload16(Aga + (size_t)64 * K + k0 + 32, &Al[buf ^ 1][lin + 64 * 32]);
            gload16(Bga + k0 + 32,                  &Bl[buf ^ 1][lin]);
            if (BNT == 128)
                gload16(Bga + (size_t)64 * K + k0 + 32, &Bl[buf ^ 1][lin + 64 * 32]);
        }
        bf16x8v af[MI], bfr[4];
        #pragma unroll
        for (int mi = 0; mi < MI; ++mi)
            af[mi] = *(const bf16x8v*)&Al[buf][(wr + mi * 16 + fr) * 32 + rsw];
        #pragma unroll
        for (int ni = 0; ni < 4; ++ni)
            bfr[ni] = *(const bf16x8v*)&Bl[buf][(wc + ni * 16 + fr) * 32 + rsw];
        #pragma unroll
        for (int mi = 0; mi < MI; ++mi)
            #pragma unroll
            for (int ni = 0; ni < 4; ++ni)
                acc[mi][ni] = __builtin_amdgcn_mfma_f32_16x16x32_bf16(
                    af[mi], bfr[ni], acc[mi][ni], 0, 0, 0);
    }

    float* Cf = (float*)Cv;
    u16*   Cb = (u16*)Cv;
    #pragma unroll
    for (int mi = 0; mi < MI; ++mi) {
        #pragma unroll
        for (int j = 0; j < 4; ++j) {
            const int r = bm * 128 + wr + mi * 16 + fq * 4 + j;
            #pragma unroll
            for (int ni = 0; ni < 4; ++ni) {
                const int c = bn * BNT + wc + ni * 16 + fr;
                float v = acc[mi][ni][j];
                if (BIAS) v += bias[c];
                if (RELU) v = fmaxf(v, 0.f);
                if (RES)  v += res[(size_t)r * N + c];
                if (OUTBF) Cb[(size_t)r * N + c] = f2bf(v);
                else       Cf[(size_t)r * N + c] = v;
            }
        }
    }
}

// ---------------------------------------------------------------------------
// 64x64-tile GEMM for N=256 ops (proj, MLP2) whose 128-row grids give only
// 1 block/CU (4 waves, barrier drain fully exposed). 64x64 -> 512 blocks =
// 2 blocks/CU = 8 waves/CU; cross-block overlap hides the vmcnt(0) drain
// (m114). Both operands L2-resident so the intensity loss is not binding.
// 4 waves 2x2 of 32x32 (MI=NI=2). LDS 16KB. Same dbuf/gload/swizzle.
// ---------------------------------------------------------------------------
template<int BIAS, int RES, int RELU, int OUTBF>
__global__ __launch_bounds__(256) void mgemm64(
    const u16* __restrict__ A, const u16* __restrict__ Bt,
    const float* __restrict__ bias, const float* __restrict__ res,
    void* __restrict__ Cv, int M, int N, int K)
{
    __shared__ u16 Al[2][64 * 32];
    __shared__ u16 Bl[2][64 * 32];
    const int tid = threadIdx.x;
    const int bm = blockIdx.x, bn = blockIdx.y;
    const int wid = tid >> 6, lane = tid & 63;
    const int wr = (wid >> 1) * 32, wc = (wid & 1) * 32;
    const int fr = lane & 15, fq = lane >> 4;

    // staging: thread t covers row t>>2 (0..63), chunk t&3 of a 64B row
    const int row = tid >> 2;
    const int lc_src = ((tid & 3) ^ ((row >> 1) & 3)) * 8;   // pre-swizzled src
    const u16* Aga = A  + (size_t)(bm * 64 + row) * K + lc_src;
    const u16* Bga = Bt + (size_t)(bn * 64 + row) * K + lc_src;
    const int lin = row * 32 + (tid & 3) * 8;

    const int rsw = (fq ^ ((fr >> 1) & 3)) * 8;

    f32x4 acc[2][2];
    #pragma unroll
    for (int i = 0; i < 2; ++i)
        #pragma unroll
        for (int j = 0; j < 2; ++j)
            acc[i][j] = f32x4{0.f, 0.f, 0.f, 0.f};

    gload16(Aga, &Al[0][lin]);
    gload16(Bga, &Bl[0][lin]);

    int buf = 0;
    for (int k0 = 0; k0 < K; k0 += 32, buf ^= 1) {
        __syncthreads();
        if (k0 + 32 < K) {
            gload16(Aga + k0 + 32, &Al[buf ^ 1][lin]);
            gload16(Bga + k0 + 32, &Bl[buf ^ 1][lin]);
        }
        bf16x8v af[2], bfr[2];
        #pragma unroll
        for (int mi = 0; mi < 2; ++mi)
            af[mi] = *(const bf16x8v*)&Al[buf][(wr + mi * 16 + fr) * 32 + rsw];
        #pragma unroll
        for (int ni = 0; ni < 2; ++ni)
            bfr[ni] = *(const bf16x8v*)&Bl[buf][(wc + ni * 16 + fr) * 32 + rsw];
        #pragma unroll
        for (int mi = 0; mi < 2; ++mi)
            #pragma unroll
            for (int ni = 0; ni < 2; ++ni)
                acc[mi][ni] = __builtin_amdgcn_mfma_f32_16x16x32_bf16(
                    af[mi], bfr[ni], acc[mi][ni], 0, 0, 0);
    }

    float* Cf = (float*)Cv;
    u16*   Cb = (u16*)Cv;
    #pragma unroll
    for (int mi = 0; mi < 2; ++mi) {
        #pragma unroll
        for (int j = 0; j < 4; ++j) {
            const int r = bm * 64 + wr + mi * 16 + fq * 4 + j;
            #pragma unroll
            for (int ni = 0; ni < 2; ++ni) {
                const int c = bn * 64 + wc + ni * 16 + fr;
                float v = acc[mi][ni][j];
                if (BIAS) v += bias[c];
                if (RELU) v = fmaxf(v, 0.f);
                if (RES)  v += res[(size_t)r * N + c];
                if (OUTBF) Cb[(size_t)r * N + c] = f2bf(v);
                else       Cf[(size_t)r * N + c] = v;
            }
        }
    }
}

// ---------------------------------------------------------------------------
// Wide-M GEMM for the LM head (R11, unchanged): 256x128 tile, 512 thr,
// non-temporal fp32 stores (1 GB logits stream bypasses L2).
// ---------------------------------------------------------------------------
template<int BIAS>
__global__ __launch_bounds__(512) void mgemm_m256(
    const u16* __restrict__ A, const u16* __restrict__ Bt,
    const float* __restrict__ bias, float* __restrict__ Cf, int N, int K)
{
    __shared__ u16 Al[2][256 * 32];   // 16KB each
    __shared__ u16 Bl[2][128 * 32];   // 8KB each
    const int tid = threadIdx.x;
    const int bm = blockIdx.x, bn = blockIdx.y;
    const int wid = tid >> 6, lane = tid & 63;
    const int wr = (wid >> 1) * 64;   // 0/64/128/192
    const int wc = (wid & 1) * 64;    // 0/64
    const int fr = lane & 15, fq = lane >> 4;

    const int l4 = tid >> 2;
    const int ch = tid & 3;
    const int lc_src = (ch ^ ((l4 >> 1) & 3)) * 8;   // pre-swizzled source col
    const u16* Aga = A  + (size_t)(bm * 256 + l4) * K + lc_src;
    const u16* Bga = Bt + (size_t)(bn * 128 + l4) * K + lc_src;
    const int lin = l4 * 32 + ch * 8;

    const int rsw = (fq ^ ((fr >> 1) & 3)) * 8;

    f32x4 acc[4][4];
    #pragma unroll
    for (int i = 0; i < 4; ++i)
        #pragma unroll
        for (int j = 0; j < 4; ++j)
            acc[i][j] = f32x4{0.f, 0.f, 0.f, 0.f};

    gload16(Aga,                   &Al[0][lin]);
    gload16(Aga + (size_t)128 * K, &Al[0][lin + 128 * 32]);
    gload16(Bga,                   &Bl[0][lin]);

    int buf = 0;
    for (int k0 = 0; k0 < K; k0 += 32, buf ^= 1) {
        __syncthreads();
        if (k0 + 32 < K) {
            gload16(Aga + k0 + 32,                   &Al[buf ^ 1][lin]);
            gload16(Aga + (size_t)128 * K + k0 + 32, &Al[buf ^ 1][lin + 128 * 32]);
            gload16(Bga + k0 + 32,                   &Bl[buf ^ 1][lin]);
        }
        bf16x8v af[4], bfr[4];
        #pragma unroll
        for (int mi = 0; mi < 4; ++mi)
            af[mi] = *(const bf16x8v*)&Al[buf][(wr + mi * 16 + fr) * 32 + rsw];
        #pragma unroll
        for (int ni = 0; ni < 4; ++ni)
            bfr[ni] = *(const bf16x8v*)&Bl[buf][(wc + ni * 16 + fr) * 32 + rsw];
        #pragma unroll
        for (int mi = 0; mi < 4; ++mi)
            #pragma unroll
            for (int ni = 0; ni < 4; ++ni)
                acc[mi][ni] = __builtin_amdgcn_mfma_f32_16x16x32_bf16(
                    af[mi], bfr[ni], acc[mi][ni], 0, 0, 0);
    }

    #pragma unroll
    for (int mi = 0; mi < 4; ++mi) {
        #pragma unroll
        for (int j = 0; j < 4; ++j) {
            const int r = bm * 256 + wr + mi * 16 + fq * 4 + j;
            #pragma unroll
            for (int ni = 0; ni < 4; ++ni) {
                const int c = bn * 128 + wc + ni * 16 + fr;
                float v = acc[mi][ni][j];
                if (BIAS) v += bias[c];
                __builtin_nontemporal_store(v, &Cf[(size_t)r * N + c]);
            }
        }
    }
}

// ---------------------------------------------------------------------------
// MFMA causal flash attention (unchanged from R5).
// ---------------------------------------------------------------------------
__global__ __launch_bounds__(256) void attn_kernel(
    const u16* __restrict__ qkv, u16* __restrict__ y)
{
    constexpr int LDK = 72;
    __shared__ u16 Kl[2][64 * LDK];
    __shared__ u16 Vt[2][64 * LDK];

    const int tid = threadIdx.x;
    const int qt = (int)gridDim.x - 1 - (int)blockIdx.x;
    const int bh = blockIdx.y;
    const int b = bh >> 2, h = bh & 3;
    const int w = tid >> 6, lane = tid & 63;
    const int fr = lane & 15, fq = lane >> 4;
    const size_t rowbase = (size_t)b * TBLK;
    const int qoff = h * HSZ, koff = EMB + h * HSZ, voff = 2 * EMB + h * HSZ;
    const int qg = qt * 64 + w * 16 + fr;

    bf16x8v qf[2];
    #pragma unroll
    for (int ks = 0; ks < 2; ++ks)
        qf[ks] = *(const bf16x8v*)&qkv[(rowbase + qg) * QKVD + qoff + ks * 32 + fq * 8];

    f32x4 yac[4];
    #pragma unroll
    for (int mi = 0; mi < 4; ++mi) yac[mi] = f32x4{0.f, 0.f, 0.f, 0.f};
    float m = -1e30f, l = 0.f;

    const int skv = tid >> 2, sc = (tid & 3) * 16;
    const u16* kbase = &qkv[(rowbase + skv) * QKVD + koff + sc];
    const u16* vbase = &qkv[(rowbase + skv) * QKVD + voff + sc];

    bf16x8v kr0 = *(const bf16x8v*)kbase;
    bf16x8v kr1 = *(const bf16x8v*)(kbase + 8);
    bf16x8v vr0 = *(const bf16x8v*)vbase;
    bf16x8v vr1 = *(const bf16x8v*)(vbase + 8);

    int buf = 0;
    for (int kv0 = 0; kv0 <= qt * 64; kv0 += 64, buf ^= 1) {
        {
            u16* Kw = &Kl[buf][skv * LDK + sc];
            *(bf16x8v*)Kw = kr0; *(bf16x8v*)(Kw + 8) = kr1;
            #pragma unroll
            for (int i = 0; i < 8; ++i) Vt[buf][(sc + i) * LDK + skv] = (u16)vr0[i];
            #pragma unroll
            for (int i = 0; i < 8; ++i) Vt[buf][(sc + 8 + i) * LDK + skv] = (u16)vr1[i];
        }
        __syncthreads();
        if (kv0 + 64 <= qt * 64) {
            const size_t off = (size_t)(kv0 + 64) * QKVD;
            kr0 = *(const bf16x8v*)(kbase + off);
            kr1 = *(const bf16x8v*)(kbase + off + 8);
            vr0 = *(const bf16x8v*)(vbase + off);
            vr1 = *(const bf16x8v*)(vbase + off + 8);
        }

        f32x4 st[4];
        __builtin_amdgcn_s_setprio(1);
        #pragma unroll
        for (int mb = 0; mb < 4; ++mb) {
            st[mb] = f32x4{0.f, 0.f, 0.f, 0.f};
            #pragma unroll
            for (int ks = 0; ks < 2; ++ks) {
                const bf16x8v kf = *(const bf16x8v*)
                    &Kl[buf][(mb * 16 + fr) * LDK + ks * 32 + fq * 8];
                st[mb] = __builtin_amdgcn_mfma_f32_16x16x32_bf16(
                    kf, qf[ks], st[mb], 0, 0, 0);
            }
        }
        __builtin_amdgcn_s_setprio(0);
        float p[4][4];
        float mloc = -1e30f;
        #pragma unroll
        for (int mb = 0; mb < 4; ++mb)
            #pragma unroll
            for (int j = 0; j < 4; ++j) {
                const int kvg = kv0 + mb * 16 + fq * 4 + j;
                const float s = (kvg <= qg) ? st[mb][j] * 0.0625f : -1e30f;
                p[mb][j] = s;
                mloc = fmaxf(mloc, s);
            }
        mloc = fmaxf(mloc, __shfl_xor(mloc, 16));
        mloc = fmaxf(mloc, __shfl_xor(mloc, 32));
        const float mnew = fmaxf(m, mloc);
        const float alpha = __expf(m - mnew);
        float rsum = 0.f;
        #pragma unroll
        for (int mb = 0; mb < 4; ++mb)
            #pragma unroll
            for (int j = 0; j < 4; ++j) {
                p[mb][j] = __expf(p[mb][j] - mnew);
                rsum += p[mb][j];
            }
        rsum += __shfl_xor(rsum, 16);
        rsum += __shfl_xor(rsum, 32);
        l = l * alpha + rsum;
        m = mnew;
        #pragma unroll
        for (int mi = 0; mi < 4; ++mi) yac[mi] *= alpha;

        u32 pk[4][2];
        #pragma unroll
        for (int mb = 0; mb < 4; ++mb) {
            pk[mb][0] = pack2(p[mb][0], p[mb][1]);
            pk[mb][1] = pack2(p[mb][2], p[mb][3]);
        }
        #pragma unroll
        for (int ksv = 0; ksv < 2; ++ksv) {
            union { u32 u[4]; bf16x8v v; } pf;
            #pragma unroll
            for (int t = 0; t < 4; ++t) {
                const int srcl = ((fq & 1) * 2 + (t >> 1)) * 16 + fr;
                const u32 lo = __shfl(pk[ksv * 2 + 0][t & 1], srcl);
                const u32 hi = __shfl(pk[ksv * 2 + 1][t & 1], srcl);
                pf.u[t] = (fq >> 1) ? hi : lo;
            }
            __builtin_amdgcn_s_setprio(1);
            #pragma unroll
            for (int mi = 0; mi < 4; ++mi) {
                const bf16x8v vf = *(const bf16x8v*)
                    &Vt[buf][(mi * 16 + fr) * LDK + ksv * 32 + fq * 8];
                yac[mi] = __builtin_amdgcn_mfma_f32_16x16x32_bf16(
                    vf, pf.v, yac[mi], 0, 0, 0);
            }
            __builtin_amdgcn_s_setprio(0);
        }
    }

    const float inv = 1.f / l;
    #pragma unroll
    for (int mi = 0; mi < 4; ++mi) {
        ushort4 o;
        o.x = f2bf(yac[mi][0] * inv);
        o.y = f2bf(yac[mi][1] * inv);
        o.z = f2bf(yac[mi][2] * inv);
        o.w = f2bf(yac[mi][3] * inv);
        *(ushort4*)&y[(rowbase + qg) * EMB + h * HSZ + mi * 16 + fq * 4] = o;
    }
}

// ---------------------------------------------------------------------------
extern "C" void kernel_launch(void* const* d_in, const int* in_sizes, int n_in,
                              void* d_out, int out_size, void* d_ws, size_t ws_size,
                              hipStream_t stream) {
    const int*   idx   = (const int*)  d_in[0];
    const float* tok   = (const float*)d_in[1];
    const float* pos   = (const float*)d_in[2];
    const float* Wq    = (const float*)d_in[3];
    const float* Wk    = (const float*)d_in[4];
    const float* Wv    = (const float*)d_in[5];
    const float* Wproj = (const float*)d_in[6];
    const float* bproj = (const float*)d_in[7];
    const float* ln1g  = (const float*)d_in[8];
    const float* ln1b  = (const float*)d_in[9];
    const float* W1    = (const float*)d_in[10];
    const float* b1    = (const float*)d_in[11];
    const float* W2    = (const float*)d_in[12];
    const float* b2    = (const float*)d_in[13];
    const float* ln2g  = (const float*)d_in[14];
    const float* ln2b  = (const float*)d_in[15];
    const float* Wlm   = (const float*)d_in[16];
    const float* blm   = (const float*)d_in[17];
    float* out = (float*)d_out;

    float* x    = (float*)d_ws;
    u16*   hb   = (u16*)(x + (size_t)BT * EMB);
    u16*   qkvb = hb + (size_t)BT * EMB;
    u16*   yb   = qkvb + (size_t)BT * QKVD;
    u16*   hid  = qkvb;  // aliases qkv+yb (dead when MLP runs)
    u16*   Wqkvt  = yb + (size_t)BT * EMB;
    u16*   Wprojt = Wqkvt  + (size_t)NLAYER * QKVD * EMB;
    u16*   W1t    = Wprojt + (size_t)NLAYER * EMB * EMB;
    u16*   W2t    = W1t    + (size_t)NLAYER * EMB * 4 * EMB;
    u16*   Wlmt   = W2t    + (size_t)NLAYER * 4 * EMB * EMB;

    transpose_all<<<2304 + (VOCAB/32)*8, dim3(32, 8), 0, stream>>>(
        Wq, Wk, Wv, Wproj, W1, W2, Wlm, Wqkvt, Wprojt, W1t, W2t, Wlmt);

    embed_ln_kernel<<<BT/4, 256, 0, stream>>>(idx, tok, pos, ln1g, ln1b, x, hb);

    for (int l = 0; l < NLAYER; ++l) {
        mgemm<64,0,0,0,1><<<dim3(BT/128, QKVD/64), 256, 0, stream>>>(
            hb, Wqkvt + (size_t)l*QKVD*EMB, nullptr, nullptr, qkvb, BT, QKVD, EMB);
        attn_kernel<<<dim3(TBLK/64, BATCH*NHEAD), 256, 0, stream>>>(qkvb, yb);
        mgemm64<1,1,0,0><<<dim3(BT/64, EMB/64), 256, 0, stream>>>(
            yb, Wprojt + (size_t)l*EMB*EMB, bproj + l*EMB, x, x, BT, EMB, EMB);
        ln_kernel<<<BT/4, 256, 0, stream>>>(x, ln2g + l*EMB, ln2b + l*EMB, hb);
        mgemm<64,1,0,1,1><<<dim3(BT/128, 4*EMB/64), 256, 0, stream>>>(
            hb, W1t + (size_t)l*EMB*4*EMB, b1 + l*4*EMB, nullptr, hid, BT, 4*EMB, EMB);
        if (l < NLAYER - 1) {
            mgemm64<1,1,0,0><<<dim3(BT/64, EMB/64), 256, 0, stream>>>(
                hid, W2t + (size_t)l*4*EMB*EMB, b2 + l*EMB, x, x, BT, EMB, 4*EMB);
            ln_kernel<<<BT/4, 256, 0, stream>>>(
                x, ln1g + (l+1)*EMB, ln1b + (l+1)*EMB, hb);
        } else {
            mgemm64<1,1,0,1><<<dim3(BT/64, EMB/64), 256, 0, stream>>>(
                hid, W2t + (size_t)l*4*EMB*EMB, b2 + l*EMB, x, hb, BT, EMB, 4*EMB);
        }
    }

    mgemm_m256<1><<<dim3(BT/256, VOCAB/128), 512, 0, stream>>>(
        hb, Wlmt, blm, out, VOCAB, EMB);
}

// Round 14
// 576.522 us; speedup vs baseline: 1.1851x; 1.0701x over previous
//
#include <hip/hip_runtime.h>
#include <hip/hip_bf16.h>

#define EMB 256
#define NHEAD 4
#define HSZ 64
#define NLAYER 3
#define TBLK 2048
#define VOCAB 32000
#define BATCH 4
#define LNEPS 1e-5f
#define BT (BATCH * TBLK)   // 8192 rows
#define QKVD (3 * EMB)      // 768

typedef __attribute__((ext_vector_type(8))) short bf16x8v;  // 8 bf16 (4 VGPRs)
typedef __attribute__((ext_vector_type(4))) float f32x4;
typedef unsigned short u16;
typedef unsigned int u32;

// round-to-nearest-even f32 -> bf16 bits
__device__ __forceinline__ u16 f2bf(float f) {
    union { float f; u32 u; } c; c.f = f;
    u32 r = c.u + 0x7fff + ((c.u >> 16) & 1);
    return (u16)(r >> 16);
}
__device__ __forceinline__ u32 pack2(float a, float b) {
    return (u32)f2bf(a) | ((u32)f2bf(b) << 16);
}

// async global->LDS, 16 bytes per lane (dest linear in lane order)
__device__ __forceinline__ void gload16(const u16* g, u16* l) {
    __builtin_amdgcn_global_load_lds(
        (__attribute__((address_space(1))) void*)g,
        (__attribute__((address_space(3))) void*)l, 16, 0, 0);
}

// ---------------------------------------------------------------------------
// Embedding + fused LN1(layer 0): writes x (fp32) and hb = LN(x) (bf16).
// ---------------------------------------------------------------------------
__global__ __launch_bounds__(256) void embed_ln_kernel(
    const int* __restrict__ idx, const float* __restrict__ tok,
    const float* __restrict__ pos, const float* __restrict__ g,
    const float* __restrict__ b, float* __restrict__ x, u16* __restrict__ hb)
{
    const int row = blockIdx.x * 4 + (threadIdx.x >> 6);
    const int t = row & (TBLK - 1);
    const int token = idx[row];
    const int e = (threadIdx.x & 63) * 4;
    const float4 tv = *(const float4*)&tok[(size_t)token * EMB + e];
    const float4 pv = *(const float4*)&pos[(size_t)t * EMB + e];
    float4 xv;
    xv.x = tv.x + pv.x; xv.y = tv.y + pv.y; xv.z = tv.z + pv.z; xv.w = tv.w + pv.w;
    *(float4*)&x[(size_t)row * EMB + e] = xv;

    float s1 = xv.x + xv.y + xv.z + xv.w;
    float s2 = xv.x * xv.x + xv.y * xv.y + xv.z * xv.z + xv.w * xv.w;
    #pragma unroll
    for (int off = 32; off >= 1; off >>= 1) {
        s1 += __shfl_xor(s1, off);
        s2 += __shfl_xor(s2, off);
    }
    const float mu  = s1 * (1.0f / EMB);
    const float var = s2 * (1.0f / EMB) - mu * mu;
    const float rs  = rsqrtf(var + LNEPS);
    const float4 gv = *(const float4*)&g[e];
    const float4 bv = *(const float4*)&b[e];
    ushort4 o;
    o.x = f2bf((xv.x - mu) * rs * gv.x + bv.x);
    o.y = f2bf((xv.y - mu) * rs * gv.y + bv.y);
    o.z = f2bf((xv.z - mu) * rs * gv.z + bv.z);
    o.w = f2bf((xv.w - mu) * rs * gv.w + bv.w);
    *(ushort4*)&hb[(size_t)row * EMB + e] = o;
}

// ---------------------------------------------------------------------------
// LayerNorm (population var) fp32 in -> bf16 out. 4 rows per block.
// ---------------------------------------------------------------------------
__global__ __launch_bounds__(256) void ln_kernel(
    const float* __restrict__ x, const float* __restrict__ g,
    const float* __restrict__ b, u16* __restrict__ out)
{
    const int row = blockIdx.x * 4 + (threadIdx.x >> 6);
    const int e = (threadIdx.x & 63) * 4;
    const float4 xv = *(const float4*)&x[(size_t)row * EMB + e];
    float s1 = xv.x + xv.y + xv.z + xv.w;
    float s2 = xv.x * xv.x + xv.y * xv.y + xv.z * xv.z + xv.w * xv.w;
    #pragma unroll
    for (int off = 32; off >= 1; off >>= 1) {
        s1 += __shfl_xor(s1, off);
        s2 += __shfl_xor(s2, off);
    }
    const float mu  = s1 * (1.0f / EMB);
    const float var = s2 * (1.0f / EMB) - mu * mu;
    const float rs  = rsqrtf(var + LNEPS);
    const float4 gv = *(const float4*)&g[e];
    const float4 bv = *(const float4*)&b[e];
    ushort4 o;
    o.x = f2bf((xv.x - mu) * rs * gv.x + bv.x);
    o.y = f2bf((xv.y - mu) * rs * gv.y + bv.y);
    o.z = f2bf((xv.z - mu) * rs * gv.z + bv.z);
    o.w = f2bf((xv.w - mu) * rs * gv.w + bv.w);
    *(ushort4*)&out[(size_t)row * EMB + e] = o;
}

// ---------------------------------------------------------------------------
// ONE fused transpose+cast dispatch for ALL weights (R11, unchanged).
// ---------------------------------------------------------------------------
__global__ __launch_bounds__(256) void transpose_all(
    const float* __restrict__ Wq, const float* __restrict__ Wk,
    const float* __restrict__ Wv, const float* __restrict__ Wp,
    const float* __restrict__ W1, const float* __restrict__ W2,
    const float* __restrict__ Wlm,
    u16* __restrict__ Wqkvt, u16* __restrict__ Wprojt, u16* __restrict__ W1t,
    u16* __restrict__ W2t, u16* __restrict__ Wlmt)
{
    __shared__ float t[32][33];
    const int tb = blockIdx.x;
    const float* W;
    u16* Wt;
    int K, N, bx, by;
    if (tb < 768) {
        const int z = tb >> 6, r = tb & 63;
        const int which = z & 3, l = z >> 2;
        switch (which) {
            case 0: W = Wq + (size_t)l*EMB*EMB; Wt = Wqkvt + (size_t)l*QKVD*EMB;             break;
            case 1: W = Wk + (size_t)l*EMB*EMB; Wt = Wqkvt + (size_t)l*QKVD*EMB + EMB*EMB;   break;
            case 2: W = Wv + (size_t)l*EMB*EMB; Wt = Wqkvt + (size_t)l*QKVD*EMB + 2*EMB*EMB; break;
            default:W = Wp + (size_t)l*EMB*EMB; Wt = Wprojt + (size_t)l*EMB*EMB;             break;
        }
        K = EMB; N = EMB; bx = r & 7; by = r >> 3;
    } else if (tb < 1536) {
        const int t2 = tb - 768, l = t2 >> 8, r = t2 & 255;
        W = W1 + (size_t)l*EMB*4*EMB; Wt = W1t + (size_t)l*EMB*4*EMB;
        K = EMB; N = 4*EMB; bx = r & 31; by = r >> 5;
    } else if (tb < 2304) {
        const int t2 = tb - 1536, l = t2 >> 8, r = t2 & 255;
        W = W2 + (size_t)l*4*EMB*EMB; Wt = W2t + (size_t)l*4*EMB*EMB;
        K = 4*EMB; N = EMB; bx = r & 7; by = r >> 3;
    } else {
        const int r = tb - 2304;
        W = Wlm; Wt = Wlmt;
        K = EMB; N = VOCAB; bx = r % 1000; by = r / 1000;
    }
    const int tx = threadIdx.x, ty = threadIdx.y;
    #pragma unroll
    for (int i = 0; i < 32; i += 8)
        t[ty + i][tx] = W[(size_t)(by * 32 + ty + i) * N + bx * 32 + tx];
    __syncthreads();
    #pragma unroll
    for (int i = 0; i < 32; i += 8)
        Wt[(size_t)(bx * 32 + ty + i) * K + by * 32 + tx] = f2bf(t[tx][ty + i]);
}

// ---------------------------------------------------------------------------
// MFMA GEMM (R5 structure): C = A[M,K] @ Bt[N,K]^T, fp32 accum.
// 128xBNT tile, BK=32, 4 waves. global_load_lds + dbuf + 1 barrier/K-iter.
// T2 chunk swizzle via pre-swizzled global source + XOR read.
// ---------------------------------------------------------------------------
template<int BNT, int BIAS, int RES, int RELU, int OUTBF>
__global__ __launch_bounds__(256) void mgemm(
    const u16* __restrict__ A, const u16* __restrict__ Bt,
    const float* __restrict__ bias, const float* __restrict__ res,
    void* __restrict__ Cv, int M, int N, int K)
{
    constexpr int MI = (BNT == 128) ? 4 : 2;
    __shared__ u16 Al[2][128 * 32];
    __shared__ u16 Bl[2][BNT * 32];
    const int tid = threadIdx.x;
    const int bm = blockIdx.x, bn = blockIdx.y;
    const int wid = tid >> 6, lane = tid & 63;
    const int wr = (BNT == 128) ? (wid >> 1) * 64 : wid * 32;
    const int wc = (BNT == 128) ? (wid & 1) * 64 : 0;
    const int fr = lane & 15, fq = lane >> 4;

    const int l4 = lane >> 2;
    const int lc_src = ((lane & 3) ^ ((l4 >> 1) & 3)) * 8;   // global col (swz)
    const u16* Aga = A  + (size_t)(bm * 128 + wid * 16 + l4) * K + lc_src;
    const u16* Bga = Bt + (size_t)(bn * BNT + wid * 16 + l4) * K + lc_src;
    const int lin = (wid * 16 + l4) * 32 + (lane & 3) * 8;   // linear LDS (u16)

    const int rsw = (fq ^ ((fr >> 1) & 3)) * 8;

    f32x4 acc[MI][4];
    #pragma unroll
    for (int i = 0; i < MI; ++i)
        #pragma unroll
        for (int j = 0; j < 4; ++j)
            acc[i][j] = f32x4{0.f, 0.f, 0.f, 0.f};

    gload16(Aga,                  &Al[0][lin]);
    gload16(Aga + (size_t)64 * K, &Al[0][lin + 64 * 32]);
    gload16(Bga,                  &Bl[0][lin]);
    if (BNT == 128) gload16(Bga + (size_t)64 * K, &Bl[0][lin + 64 * 32]);

    int buf = 0;
    for (int k0 = 0; k0 < K; k0 += 32, buf ^= 1) {
        __syncthreads();
        if (k0 + 32 < K) {
            gload16(Aga + k0 + 32,                  &Al[buf ^ 1][lin]);
            gload16(Aga + (size_t)64 * K + k0 + 32, &Al[buf ^ 1][lin + 64 * 32]);
            gload16(Bga + k0 + 32,                  &Bl[buf ^ 1][lin]);
            if (BNT == 128)
                gload16(Bga + (size_t)64 * K + k0 + 32, &Bl[buf ^ 1][lin + 64 * 32]);
        }
        bf16x8v af[MI], bfr[4];
        #pragma unroll
        for (int mi = 0; mi < MI; ++mi)
            af[mi] = *(const bf16x8v*)&Al[buf][(wr + mi * 16 + fr) * 32 + rsw];
        #pragma unroll
        for (int ni = 0; ni < 4; ++ni)
            bfr[ni] = *(const bf16x8v*)&Bl[buf][(wc + ni * 16 + fr) * 32 + rsw];
        #pragma unroll
        for (int mi = 0; mi < MI; ++mi)
            #pragma unroll
            for (int ni = 0; ni < 4; ++ni)
                acc[mi][ni] = __builtin_amdgcn_mfma_f32_16x16x32_bf16(
                    af[mi], bfr[ni], acc[mi][ni], 0, 0, 0);
    }

    float* Cf = (float*)Cv;
    u16*   Cb = (u16*)Cv;
    #pragma unroll
    for (int mi = 0; mi < MI; ++mi) {
        #pragma unroll
        for (int j = 0; j < 4; ++j) {
            const int r = bm * 128 + wr + mi * 16 + fq * 4 + j;
            #pragma unroll
            for (int ni = 0; ni < 4; ++ni) {
                const int c = bn * BNT + wc + ni * 16 + fr;
                float v = acc[mi][ni][j];
                if (BIAS) v += bias[c];
                if (RELU) v = fmaxf(v, 0.f);
                if (RES)  v += res[(size_t)r * N + c];
                if (OUTBF) Cb[(size_t)r * N + c] = f2bf(v);
                else       Cf[(size_t)r * N + c] = v;
            }
        }
    }
}

// ---------------------------------------------------------------------------
// 64x64-tile GEMM for N=256 ops (proj, MLP2): 512 blocks = 2 blocks/CU,
// cross-block overlap hides the barrier drain (R12, unchanged).
// ---------------------------------------------------------------------------
template<int BIAS, int RES, int RELU, int OUTBF>
__global__ __launch_bounds__(256) void mgemm64(
    const u16* __restrict__ A, const u16* __restrict__ Bt,
    const float* __restrict__ bias, const float* __restrict__ res,
    void* __restrict__ Cv, int M, int N, int K)
{
    __shared__ u16 Al[2][64 * 32];
    __shared__ u16 Bl[2][64 * 32];
    const int tid = threadIdx.x;
    const int bm = blockIdx.x, bn = blockIdx.y;
    const int wid = tid >> 6, lane = tid & 63;
    const int wr = (wid >> 1) * 32, wc = (wid & 1) * 32;
    const int fr = lane & 15, fq = lane >> 4;

    const int row = tid >> 2;
    const int lc_src = ((tid & 3) ^ ((row >> 1) & 3)) * 8;   // pre-swizzled src
    const u16* Aga = A  + (size_t)(bm * 64 + row) * K + lc_src;
    const u16* Bga = Bt + (size_t)(bn * 64 + row) * K + lc_src;
    const int lin = row * 32 + (tid & 3) * 8;

    const int rsw = (fq ^ ((fr >> 1) & 3)) * 8;

    f32x4 acc[2][2];
    #pragma unroll
    for (int i = 0; i < 2; ++i)
        #pragma unroll
        for (int j = 0; j < 2; ++j)
            acc[i][j] = f32x4{0.f, 0.f, 0.f, 0.f};

    gload16(Aga, &Al[0][lin]);
    gload16(Bga, &Bl[0][lin]);

    int buf = 0;
    for (int k0 = 0; k0 < K; k0 += 32, buf ^= 1) {
        __syncthreads();
        if (k0 + 32 < K) {
            gload16(Aga + k0 + 32, &Al[buf ^ 1][lin]);
            gload16(Bga + k0 + 32, &Bl[buf ^ 1][lin]);
        }
        bf16x8v af[2], bfr[2];
        #pragma unroll
        for (int mi = 0; mi < 2; ++mi)
            af[mi] = *(const bf16x8v*)&Al[buf][(wr + mi * 16 + fr) * 32 + rsw];
        #pragma unroll
        for (int ni = 0; ni < 2; ++ni)
            bfr[ni] = *(const bf16x8v*)&Bl[buf][(wc + ni * 16 + fr) * 32 + rsw];
        #pragma unroll
        for (int mi = 0; mi < 2; ++mi)
            #pragma unroll
            for (int ni = 0; ni < 2; ++ni)
                acc[mi][ni] = __builtin_amdgcn_mfma_f32_16x16x32_bf16(
                    af[mi], bfr[ni], acc[mi][ni], 0, 0, 0);
    }

    float* Cf = (float*)Cv;
    u16*   Cb = (u16*)Cv;
    #pragma unroll
    for (int mi = 0; mi < 2; ++mi) {
        #pragma unroll
        for (int j = 0; j < 4; ++j) {
            const int r = bm * 64 + wr + mi * 16 + fq * 4 + j;
            #pragma unroll
            for (int ni = 0; ni < 2; ++ni) {
                const int c = bn * 64 + wc + ni * 16 + fr;
                float v = acc[mi][ni][j];
                if (BIAS) v += bias[c];
                if (RELU) v = fmaxf(v, 0.f);
                if (RES)  v += res[(size_t)r * N + c];
                if (OUTBF) Cb[(size_t)r * N + c] = f2bf(v);
                else       Cf[(size_t)r * N + c] = v;
            }
        }
    }
}

// ---------------------------------------------------------------------------
// Wide-M GEMM for the LM head (R11, unchanged): 256x128 tile, 512 thr,
// non-temporal fp32 stores (1 GB logits stream bypasses L2).
// ---------------------------------------------------------------------------
template<int BIAS>
__global__ __launch_bounds__(512) void mgemm_m256(
    const u16* __restrict__ A, const u16* __restrict__ Bt,
    const float* __restrict__ bias, float* __restrict__ Cf, int N, int K)
{
    __shared__ u16 Al[2][256 * 32];   // 16KB each
    __shared__ u16 Bl[2][128 * 32];   // 8KB each
    const int tid = threadIdx.x;
    const int bm = blockIdx.x, bn = blockIdx.y;
    const int wid = tid >> 6, lane = tid & 63;
    const int wr = (wid >> 1) * 64;   // 0/64/128/192
    const int wc = (wid & 1) * 64;    // 0/64
    const int fr = lane & 15, fq = lane >> 4;

    const int l4 = tid >> 2;
    const int ch = tid & 3;
    const int lc_src = (ch ^ ((l4 >> 1) & 3)) * 8;   // pre-swizzled source col
    const u16* Aga = A  + (size_t)(bm * 256 + l4) * K + lc_src;
    const u16* Bga = Bt + (size_t)(bn * 128 + l4) * K + lc_src;
    const int lin = l4 * 32 + ch * 8;

    const int rsw = (fq ^ ((fr >> 1) & 3)) * 8;

    f32x4 acc[4][4];
    #pragma unroll
    for (int i = 0; i < 4; ++i)
        #pragma unroll
        for (int j = 0; j < 4; ++j)
            acc[i][j] = f32x4{0.f, 0.f, 0.f, 0.f};

    gload16(Aga,                   &Al[0][lin]);
    gload16(Aga + (size_t)128 * K, &Al[0][lin + 128 * 32]);
    gload16(Bga,                   &Bl[0][lin]);

    int buf = 0;
    for (int k0 = 0; k0 < K; k0 += 32, buf ^= 1) {
        __syncthreads();
        if (k0 + 32 < K) {
            gload16(Aga + k0 + 32,                   &Al[buf ^ 1][lin]);
            gload16(Aga + (size_t)128 * K + k0 + 32, &Al[buf ^ 1][lin + 128 * 32]);
            gload16(Bga + k0 + 32,                   &Bl[buf ^ 1][lin]);
        }
        bf16x8v af[4], bfr[4];
        #pragma unroll
        for (int mi = 0; mi < 4; ++mi)
            af[mi] = *(const bf16x8v*)&Al[buf][(wr + mi * 16 + fr) * 32 + rsw];
        #pragma unroll
        for (int ni = 0; ni < 4; ++ni)
            bfr[ni] = *(const bf16x8v*)&Bl[buf][(wc + ni * 16 + fr) * 32 + rsw];
        #pragma unroll
        for (int mi = 0; mi < 4; ++mi)
            #pragma unroll
            for (int ni = 0; ni < 4; ++ni)
                acc[mi][ni] = __builtin_amdgcn_mfma_f32_16x16x32_bf16(
                    af[mi], bfr[ni], acc[mi][ni], 0, 0, 0);
    }

    #pragma unroll
    for (int mi = 0; mi < 4; ++mi) {
        #pragma unroll
        for (int j = 0; j < 4; ++j) {
            const int r = bm * 256 + wr + mi * 16 + fq * 4 + j;
            #pragma unroll
            for (int ni = 0; ni < 4; ++ni) {
                const int c = bn * 128 + wc + ni * 16 + fr;
                float v = acc[mi][ni][j];
                if (BIAS) v += bias[c];
                __builtin_nontemporal_store(v, &Cf[(size_t)r * N + c]);
            }
        }
    }
}

// ---------------------------------------------------------------------------
// MFMA causal flash attention. R13 change: load-balanced qt mapping.
// All 512 blocks are co-resident (36KB LDS -> 2 blocks/CU); linear blocks
// L and L+256 land on the same CU under both round-robin models and share
// blockIdx.x. qt = (bh<8) ? x : 31-x makes the co-resident pair's work
// complementary: (x+1) + (32-x) = 33 kv-tiles per CU, vs up to 64 before.
// ---------------------------------------------------------------------------
__global__ __launch_bounds__(256) void attn_kernel(
    const u16* __restrict__ qkv, u16* __restrict__ y)
{
    constexpr int LDK = 72;
    __shared__ u16 Kl[2][64 * LDK];
    __shared__ u16 Vt[2][64 * LDK];

    const int tid = threadIdx.x;
    const int bh = blockIdx.y;
    const int qt = (bh < 8) ? (int)blockIdx.x
                            : (int)gridDim.x - 1 - (int)blockIdx.x;
    const int b = bh >> 2, h = bh & 3;
    const int w = tid >> 6, lane = tid & 63;
    const int fr = lane & 15, fq = lane >> 4;
    const size_t rowbase = (size_t)b * TBLK;
    const int qoff = h * HSZ, koff = EMB + h * HSZ, voff = 2 * EMB + h * HSZ;
    const int qg = qt * 64 + w * 16 + fr;

    bf16x8v qf[2];
    #pragma unroll
    for (int ks = 0; ks < 2; ++ks)
        qf[ks] = *(const bf16x8v*)&qkv[(rowbase + qg) * QKVD + qoff + ks * 32 + fq * 8];

    f32x4 yac[4];
    #pragma unroll
    for (int mi = 0; mi < 4; ++mi) yac[mi] = f32x4{0.f, 0.f, 0.f, 0.f};
    float m = -1e30f, l = 0.f;

    const int skv = tid >> 2, sc = (tid & 3) * 16;
    const u16* kbase = &qkv[(rowbase + skv) * QKVD + koff + sc];
    const u16* vbase = &qkv[(rowbase + skv) * QKVD + voff + sc];

    bf16x8v kr0 = *(const bf16x8v*)kbase;
    bf16x8v kr1 = *(const bf16x8v*)(kbase + 8);
    bf16x8v vr0 = *(const bf16x8v*)vbase;
    bf16x8v vr1 = *(const bf16x8v*)(vbase + 8);

    int buf = 0;
    for (int kv0 = 0; kv0 <= qt * 64; kv0 += 64, buf ^= 1) {
        {
            u16* Kw = &Kl[buf][skv * LDK + sc];
            *(bf16x8v*)Kw = kr0; *(bf16x8v*)(Kw + 8) = kr1;
            #pragma unroll
            for (int i = 0; i < 8; ++i) Vt[buf][(sc + i) * LDK + skv] = (u16)vr0[i];
            #pragma unroll
            for (int i = 0; i < 8; ++i) Vt[buf][(sc + 8 + i) * LDK + skv] = (u16)vr1[i];
        }
        __syncthreads();
        if (kv0 + 64 <= qt * 64) {
            const size_t off = (size_t)(kv0 + 64) * QKVD;
            kr0 = *(const bf16x8v*)(kbase + off);
            kr1 = *(const bf16x8v*)(kbase + off + 8);
            vr0 = *(const bf16x8v*)(vbase + off);
            vr1 = *(const bf16x8v*)(vbase + off + 8);
        }

        f32x4 st[4];
        __builtin_amdgcn_s_setprio(1);
        #pragma unroll
        for (int mb = 0; mb < 4; ++mb) {
            st[mb] = f32x4{0.f, 0.f, 0.f, 0.f};
            #pragma unroll
            for (int ks = 0; ks < 2; ++ks) {
                const bf16x8v kf = *(const bf16x8v*)
                    &Kl[buf][(mb * 16 + fr) * LDK + ks * 32 + fq * 8];
                st[mb] = __builtin_amdgcn_mfma_f32_16x16x32_bf16(
                    kf, qf[ks], st[mb], 0, 0, 0);
            }
        }
        __builtin_amdgcn_s_setprio(0);
        float p[4][4];
        float mloc = -1e30f;
        #pragma unroll
        for (int mb = 0; mb < 4; ++mb)
            #pragma unroll
            for (int j = 0; j < 4; ++j) {
                const int kvg = kv0 + mb * 16 + fq * 4 + j;
                const float s = (kvg <= qg) ? st[mb][j] * 0.0625f : -1e30f;
                p[mb][j] = s;
                mloc = fmaxf(mloc, s);
            }
        mloc = fmaxf(mloc, __shfl_xor(mloc, 16));
        mloc = fmaxf(mloc, __shfl_xor(mloc, 32));
        const float mnew = fmaxf(m, mloc);
        const float alpha = __expf(m - mnew);
        float rsum = 0.f;
        #pragma unroll
        for (int mb = 0; mb < 4; ++mb)
            #pragma unroll
            for (int j = 0; j < 4; ++j) {
                p[mb][j] = __expf(p[mb][j] - mnew);
                rsum += p[mb][j];
            }
        rsum += __shfl_xor(rsum, 16);
        rsum += __shfl_xor(rsum, 32);
        l = l * alpha + rsum;
        m = mnew;
        #pragma unroll
        for (int mi = 0; mi < 4; ++mi) yac[mi] *= alpha;

        u32 pk[4][2];
        #pragma unroll
        for (int mb = 0; mb < 4; ++mb) {
            pk[mb][0] = pack2(p[mb][0], p[mb][1]);
            pk[mb][1] = pack2(p[mb][2], p[mb][3]);
        }
        #pragma unroll
        for (int ksv = 0; ksv < 2; ++ksv) {
            union { u32 u[4]; bf16x8v v; } pf;
            #pragma unroll
            for (int t = 0; t < 4; ++t) {
                const int srcl = ((fq & 1) * 2 + (t >> 1)) * 16 + fr;
                const u32 lo = __shfl(pk[ksv * 2 + 0][t & 1], srcl);
                const u32 hi = __shfl(pk[ksv * 2 + 1][t & 1], srcl);
                pf.u[t] = (fq >> 1) ? hi : lo;
            }
            __builtin_amdgcn_s_setprio(1);
            #pragma unroll
            for (int mi = 0; mi < 4; ++mi) {
                const bf16x8v vf = *(const bf16x8v*)
                    &Vt[buf][(mi * 16 + fr) * LDK + ksv * 32 + fq * 8];
                yac[mi] = __builtin_amdgcn_mfma_f32_16x16x32_bf16(
                    vf, pf.v, yac[mi], 0, 0, 0);
            }
            __builtin_amdgcn_s_setprio(0);
        }
    }

    const float inv = 1.f / l;
    #pragma unroll
    for (int mi = 0; mi < 4; ++mi) {
        ushort4 o;
        o.x = f2bf(yac[mi][0] * inv);
        o.y = f2bf(yac[mi][1] * inv);
        o.z = f2bf(yac[mi][2] * inv);
        o.w = f2bf(yac[mi][3] * inv);
        *(ushort4*)&y[(rowbase + qg) * EMB + h * HSZ + mi * 16 + fq * 4] = o;
    }
}

// ---------------------------------------------------------------------------
extern "C" void kernel_launch(void* const* d_in, const int* in_sizes, int n_in,
                              void* d_out, int out_size, void* d_ws, size_t ws_size,
                              hipStream_t stream) {
    const int*   idx   = (const int*)  d_in[0];
    const float* tok   = (const float*)d_in[1];
    const float* pos   = (const float*)d_in[2];
    const float* Wq    = (const float*)d_in[3];
    const float* Wk    = (const float*)d_in[4];
    const float* Wv    = (const float*)d_in[5];
    const float* Wproj = (const float*)d_in[6];
    const float* bproj = (const float*)d_in[7];
    const float* ln1g  = (const float*)d_in[8];
    const float* ln1b  = (const float*)d_in[9];
    const float* W1    = (const float*)d_in[10];
    const float* b1    = (const float*)d_in[11];
    const float* W2    = (const float*)d_in[12];
    const float* b2    = (const float*)d_in[13];
    const float* ln2g  = (const float*)d_in[14];
    const float* ln2b  = (const float*)d_in[15];
    const float* Wlm   = (const float*)d_in[16];
    const float* blm   = (const float*)d_in[17];
    float* out = (float*)d_out;

    float* x    = (float*)d_ws;
    u16*   hb   = (u16*)(x + (size_t)BT * EMB);
    u16*   qkvb = hb + (size_t)BT * EMB;
    u16*   yb   = qkvb + (size_t)BT * QKVD;
    u16*   hid  = qkvb;  // aliases qkv+yb (dead when MLP runs)
    u16*   Wqkvt  = yb + (size_t)BT * EMB;
    u16*   Wprojt = Wqkvt  + (size_t)NLAYER * QKVD * EMB;
    u16*   W1t    = Wprojt + (size_t)NLAYER * EMB * EMB;
    u16*   W2t    = W1t    + (size_t)NLAYER * EMB * 4 * EMB;
    u16*   Wlmt   = W2t    + (size_t)NLAYER * 4 * EMB * EMB;

    transpose_all<<<2304 + (VOCAB/32)*8, dim3(32, 8), 0, stream>>>(
        Wq, Wk, Wv, Wproj, W1, W2, Wlm, Wqkvt, Wprojt, W1t, W2t, Wlmt);

    embed_ln_kernel<<<BT/4, 256, 0, stream>>>(idx, tok, pos, ln1g, ln1b, x, hb);

    for (int l = 0; l < NLAYER; ++l) {
        mgemm<64,0,0,0,1><<<dim3(BT/128, QKVD/64), 256, 0, stream>>>(
            hb, Wqkvt + (size_t)l*QKVD*EMB, nullptr, nullptr, qkvb, BT, QKVD, EMB);
        attn_kernel<<<dim3(TBLK/64, BATCH*NHEAD), 256, 0, stream>>>(qkvb, yb);
        mgemm64<1,1,0,0><<<dim3(BT/64, EMB/64), 256, 0, stream>>>(
            yb, Wprojt + (size_t)l*EMB*EMB, bproj + l*EMB, x, x, BT, EMB, EMB);
        ln_kernel<<<BT/4, 256, 0, stream>>>(x, ln2g + l*EMB, ln2b + l*EMB, hb);
        mgemm<64,1,0,1,1><<<dim3(BT/128, 4*EMB/64), 256, 0, stream>>>(
            hb, W1t + (size_t)l*EMB*4*EMB, b1 + l*4*EMB, nullptr, hid, BT, 4*EMB, EMB);
        if (l < NLAYER - 1) {
            mgemm64<1,1,0,0><<<dim3(BT/64, EMB/64), 256, 0, stream>>>(
                hid, W2t + (size_t)l*4*EMB*EMB, b2 + l*EMB, x, x, BT, EMB, 4*EMB);
            ln_kernel<<<BT/4, 256, 0, stream>>>(
                x, ln1g + (l+1)*EMB, ln1b + (l+1)*EMB, hb);
        } else {
            mgemm64<1,1,0,1><<<dim3(BT/64, EMB/64), 256, 0, stream>>>(
                hid, W2t + (size_t)l*4*EMB*EMB, b2 + l*EMB, x, hb, BT, EMB, 4*EMB);
        }
    }

    mgemm_m256<1><<<dim3(BT/256, VOCAB/128), 512, 0, stream>>>(
        hb, Wlmt, blm, out, VOCAB, EMB);
}

// Round 15
// 571.148 us; speedup vs baseline: 1.1963x; 1.0094x over previous
//
#include <hip/hip_runtime.h>
#include <hip/hip_bf16.h>

#define EMB 256
#define NHEAD 4
#define HSZ 64
#define NLAYER 3
#define TBLK 2048
#define VOCAB 32000
#define BATCH 4
#define LNEPS 1e-5f
#define BT (BATCH * TBLK)   // 8192 rows
#define QKVD (3 * EMB)      // 768

typedef __attribute__((ext_vector_type(8))) short bf16x8v;  // 8 bf16 (4 VGPRs)
typedef __attribute__((ext_vector_type(4))) float f32x4;
typedef unsigned short u16;
typedef unsigned int u32;

// round-to-nearest-even f32 -> bf16 bits
__device__ __forceinline__ u16 f2bf(float f) {
    union { float f; u32 u; } c; c.f = f;
    u32 r = c.u + 0x7fff + ((c.u >> 16) & 1);
    return (u16)(r >> 16);
}
__device__ __forceinline__ u32 pack2(float a, float b) {
    return (u32)f2bf(a) | ((u32)f2bf(b) << 16);
}

// async global->LDS, 16 bytes per lane (dest linear in lane order)
__device__ __forceinline__ void gload16(const u16* g, u16* l) {
    __builtin_amdgcn_global_load_lds(
        (__attribute__((address_space(1))) void*)g,
        (__attribute__((address_space(3))) void*)l, 16, 0, 0);
}

// ---------------------------------------------------------------------------
// Embedding + fused LN1(layer 0): writes x (fp32) and hb = LN(x) (bf16).
// ---------------------------------------------------------------------------
__global__ __launch_bounds__(256) void embed_ln_kernel(
    const int* __restrict__ idx, const float* __restrict__ tok,
    const float* __restrict__ pos, const float* __restrict__ g,
    const float* __restrict__ b, float* __restrict__ x, u16* __restrict__ hb)
{
    const int row = blockIdx.x * 4 + (threadIdx.x >> 6);
    const int t = row & (TBLK - 1);
    const int token = idx[row];
    const int e = (threadIdx.x & 63) * 4;
    const float4 tv = *(const float4*)&tok[(size_t)token * EMB + e];
    const float4 pv = *(const float4*)&pos[(size_t)t * EMB + e];
    float4 xv;
    xv.x = tv.x + pv.x; xv.y = tv.y + pv.y; xv.z = tv.z + pv.z; xv.w = tv.w + pv.w;
    *(float4*)&x[(size_t)row * EMB + e] = xv;

    float s1 = xv.x + xv.y + xv.z + xv.w;
    float s2 = xv.x * xv.x + xv.y * xv.y + xv.z * xv.z + xv.w * xv.w;
    #pragma unroll
    for (int off = 32; off >= 1; off >>= 1) {
        s1 += __shfl_xor(s1, off);
        s2 += __shfl_xor(s2, off);
    }
    const float mu  = s1 * (1.0f / EMB);
    const float var = s2 * (1.0f / EMB) - mu * mu;
    const float rs  = rsqrtf(var + LNEPS);
    const float4 gv = *(const float4*)&g[e];
    const float4 bv = *(const float4*)&b[e];
    ushort4 o;
    o.x = f2bf((xv.x - mu) * rs * gv.x + bv.x);
    o.y = f2bf((xv.y - mu) * rs * gv.y + bv.y);
    o.z = f2bf((xv.z - mu) * rs * gv.z + bv.z);
    o.w = f2bf((xv.w - mu) * rs * gv.w + bv.w);
    *(ushort4*)&hb[(size_t)row * EMB + e] = o;
}

// ---------------------------------------------------------------------------
// LayerNorm (population var) fp32 in -> bf16 out. 4 rows per block.
// ---------------------------------------------------------------------------
__global__ __launch_bounds__(256) void ln_kernel(
    const float* __restrict__ x, const float* __restrict__ g,
    const float* __restrict__ b, u16* __restrict__ out)
{
    const int row = blockIdx.x * 4 + (threadIdx.x >> 6);
    const int e = (threadIdx.x & 63) * 4;
    const float4 xv = *(const float4*)&x[(size_t)row * EMB + e];
    float s1 = xv.x + xv.y + xv.z + xv.w;
    float s2 = xv.x * xv.x + xv.y * xv.y + xv.z * xv.z + xv.w * xv.w;
    #pragma unroll
    for (int off = 32; off >= 1; off >>= 1) {
        s1 += __shfl_xor(s1, off);
        s2 += __shfl_xor(s2, off);
    }
    const float mu  = s1 * (1.0f / EMB);
    const float var = s2 * (1.0f / EMB) - mu * mu;
    const float rs  = rsqrtf(var + LNEPS);
    const float4 gv = *(const float4*)&g[e];
    const float4 bv = *(const float4*)&b[e];
    ushort4 o;
    o.x = f2bf((xv.x - mu) * rs * gv.x + bv.x);
    o.y = f2bf((xv.y - mu) * rs * gv.y + bv.y);
    o.z = f2bf((xv.z - mu) * rs * gv.z + bv.z);
    o.w = f2bf((xv.w - mu) * rs * gv.w + bv.w);
    *(ushort4*)&out[(size_t)row * EMB + e] = o;
}

// ---------------------------------------------------------------------------
// ONE fused transpose+cast dispatch for ALL weights (R11, unchanged).
// ---------------------------------------------------------------------------
__global__ __launch_bounds__(256) void transpose_all(
    const float* __restrict__ Wq, const float* __restrict__ Wk,
    const float* __restrict__ Wv, const float* __restrict__ Wp,
    const float* __restrict__ W1, const float* __restrict__ W2,
    const float* __restrict__ Wlm,
    u16* __restrict__ Wqkvt, u16* __restrict__ Wprojt, u16* __restrict__ W1t,
    u16* __restrict__ W2t, u16* __restrict__ Wlmt)
{
    __shared__ float t[32][33];
    const int tb = blockIdx.x;
    const float* W;
    u16* Wt;
    int K, N, bx, by;
    if (tb < 768) {
        const int z = tb >> 6, r = tb & 63;
        const int which = z & 3, l = z >> 2;
        switch (which) {
            case 0: W = Wq + (size_t)l*EMB*EMB; Wt = Wqkvt + (size_t)l*QKVD*EMB;             break;
            case 1: W = Wk + (size_t)l*EMB*EMB; Wt = Wqkvt + (size_t)l*QKVD*EMB + EMB*EMB;   break;
            case 2: W = Wv + (size_t)l*EMB*EMB; Wt = Wqkvt + (size_t)l*QKVD*EMB + 2*EMB*EMB; break;
            default:W = Wp + (size_t)l*EMB*EMB; Wt = Wprojt + (size_t)l*EMB*EMB;             break;
        }
        K = EMB; N = EMB; bx = r & 7; by = r >> 3;
    } else if (tb < 1536) {
        const int t2 = tb - 768, l = t2 >> 8, r = t2 & 255;
        W = W1 + (size_t)l*EMB*4*EMB; Wt = W1t + (size_t)l*EMB*4*EMB;
        K = EMB; N = 4*EMB; bx = r & 31; by = r >> 5;
    } else if (tb < 2304) {
        const int t2 = tb - 1536, l = t2 >> 8, r = t2 & 255;
        W = W2 + (size_t)l*4*EMB*EMB; Wt = W2t + (size_t)l*4*EMB*EMB;
        K = 4*EMB; N = EMB; bx = r & 7; by = r >> 3;
    } else {
        const int r = tb - 2304;
        W = Wlm; Wt = Wlmt;
        K = EMB; N = VOCAB; bx = r % 1000; by = r / 1000;
    }
    const int tx = threadIdx.x, ty = threadIdx.y;
    #pragma unroll
    for (int i = 0; i < 32; i += 8)
        t[ty + i][tx] = W[(size_t)(by * 32 + ty + i) * N + bx * 32 + tx];
    __syncthreads();
    #pragma unroll
    for (int i = 0; i < 32; i += 8)
        Wt[(size_t)(bx * 32 + ty + i) * K + by * 32 + tx] = f2bf(t[tx][ty + i]);
}

// ---------------------------------------------------------------------------
// 64x64-tile GEMM (R12 structure) — now used for ALL layer GEMMs (QKV, proj,
// MLP1, MLP2). High block count (1536-2048) = 6-8 blocks/CU; cross-block
// overlap hides the 2-phase barrier drain (m114). Operands L2-resident so
// the intensity loss vs 128-row tiles is not binding.
// 4 waves 2x2 of 32x32 (MI=NI=2). LDS 16KB. dbuf + gload_lds + T2 swizzle.
// ---------------------------------------------------------------------------
template<int BIAS, int RES, int RELU, int OUTBF>
__global__ __launch_bounds__(256) void mgemm64(
    const u16* __restrict__ A, const u16* __restrict__ Bt,
    const float* __restrict__ bias, const float* __restrict__ res,
    void* __restrict__ Cv, int M, int N, int K)
{
    __shared__ u16 Al[2][64 * 32];
    __shared__ u16 Bl[2][64 * 32];
    const int tid = threadIdx.x;
    const int bm = blockIdx.x, bn = blockIdx.y;
    const int wid = tid >> 6, lane = tid & 63;
    const int wr = (wid >> 1) * 32, wc = (wid & 1) * 32;
    const int fr = lane & 15, fq = lane >> 4;

    const int row = tid >> 2;
    const int lc_src = ((tid & 3) ^ ((row >> 1) & 3)) * 8;   // pre-swizzled src
    const u16* Aga = A  + (size_t)(bm * 64 + row) * K + lc_src;
    const u16* Bga = Bt + (size_t)(bn * 64 + row) * K + lc_src;
    const int lin = row * 32 + (tid & 3) * 8;

    const int rsw = (fq ^ ((fr >> 1) & 3)) * 8;

    f32x4 acc[2][2];
    #pragma unroll
    for (int i = 0; i < 2; ++i)
        #pragma unroll
        for (int j = 0; j < 2; ++j)
            acc[i][j] = f32x4{0.f, 0.f, 0.f, 0.f};

    gload16(Aga, &Al[0][lin]);
    gload16(Bga, &Bl[0][lin]);

    int buf = 0;
    for (int k0 = 0; k0 < K; k0 += 32, buf ^= 1) {
        __syncthreads();
        if (k0 + 32 < K) {
            gload16(Aga + k0 + 32, &Al[buf ^ 1][lin]);
            gload16(Bga + k0 + 32, &Bl[buf ^ 1][lin]);
        }
        bf16x8v af[2], bfr[2];
        #pragma unroll
        for (int mi = 0; mi < 2; ++mi)
            af[mi] = *(const bf16x8v*)&Al[buf][(wr + mi * 16 + fr) * 32 + rsw];
        #pragma unroll
        for (int ni = 0; ni < 2; ++ni)
            bfr[ni] = *(const bf16x8v*)&Bl[buf][(wc + ni * 16 + fr) * 32 + rsw];
        #pragma unroll
        for (int mi = 0; mi < 2; ++mi)
            #pragma unroll
            for (int ni = 0; ni < 2; ++ni)
                acc[mi][ni] = __builtin_amdgcn_mfma_f32_16x16x32_bf16(
                    af[mi], bfr[ni], acc[mi][ni], 0, 0, 0);
    }

    float* Cf = (float*)Cv;
    u16*   Cb = (u16*)Cv;
    #pragma unroll
    for (int mi = 0; mi < 2; ++mi) {
        #pragma unroll
        for (int j = 0; j < 4; ++j) {
            const int r = bm * 64 + wr + mi * 16 + fq * 4 + j;
            #pragma unroll
            for (int ni = 0; ni < 2; ++ni) {
                const int c = bn * 64 + wc + ni * 16 + fr;
                float v = acc[mi][ni][j];
                if (BIAS) v += bias[c];
                if (RELU) v = fmaxf(v, 0.f);
                if (RES)  v += res[(size_t)r * N + c];
                if (OUTBF) Cb[(size_t)r * N + c] = f2bf(v);
                else       Cf[(size_t)r * N + c] = v;
            }
        }
    }
}

// ---------------------------------------------------------------------------
// Wide-M GEMM for the LM head (R11, unchanged): 256x128 tile, 512 thr,
// non-temporal fp32 stores (1 GB logits stream bypasses L2).
// ---------------------------------------------------------------------------
template<int BIAS>
__global__ __launch_bounds__(512) void mgemm_m256(
    const u16* __restrict__ A, const u16* __restrict__ Bt,
    const float* __restrict__ bias, float* __restrict__ Cf, int N, int K)
{
    __shared__ u16 Al[2][256 * 32];   // 16KB each
    __shared__ u16 Bl[2][128 * 32];   // 8KB each
    const int tid = threadIdx.x;
    const int bm = blockIdx.x, bn = blockIdx.y;
    const int wid = tid >> 6, lane = tid & 63;
    const int wr = (wid >> 1) * 64;   // 0/64/128/192
    const int wc = (wid & 1) * 64;    // 0/64
    const int fr = lane & 15, fq = lane >> 4;

    const int l4 = tid >> 2;
    const int ch = tid & 3;
    const int lc_src = (ch ^ ((l4 >> 1) & 3)) * 8;   // pre-swizzled source col
    const u16* Aga = A  + (size_t)(bm * 256 + l4) * K + lc_src;
    const u16* Bga = Bt + (size_t)(bn * 128 + l4) * K + lc_src;
    const int lin = l4 * 32 + ch * 8;

    const int rsw = (fq ^ ((fr >> 1) & 3)) * 8;

    f32x4 acc[4][4];
    #pragma unroll
    for (int i = 0; i < 4; ++i)
        #pragma unroll
        for (int j = 0; j < 4; ++j)
            acc[i][j] = f32x4{0.f, 0.f, 0.f, 0.f};

    gload16(Aga,                   &Al[0][lin]);
    gload16(Aga + (size_t)128 * K, &Al[0][lin + 128 * 32]);
    gload16(Bga,                   &Bl[0][lin]);

    int buf = 0;
    for (int k0 = 0; k0 < K; k0 += 32, buf ^= 1) {
        __syncthreads();
        if (k0 + 32 < K) {
            gload16(Aga + k0 + 32,                   &Al[buf ^ 1][lin]);
            gload16(Aga + (size_t)128 * K + k0 + 32, &Al[buf ^ 1][lin + 128 * 32]);
            gload16(Bga + k0 + 32,                   &Bl[buf ^ 1][lin]);
        }
        bf16x8v af[4], bfr[4];
        #pragma unroll
        for (int mi = 0; mi < 4; ++mi)
            af[mi] = *(const bf16x8v*)&Al[buf][(wr + mi * 16 + fr) * 32 + rsw];
        #pragma unroll
        for (int ni = 0; ni < 4; ++ni)
            bfr[ni] = *(const bf16x8v*)&Bl[buf][(wc + ni * 16 + fr) * 32 + rsw];
        #pragma unroll
        for (int mi = 0; mi < 4; ++mi)
            #pragma unroll
            for (int ni = 0; ni < 4; ++ni)
                acc[mi][ni] = __builtin_amdgcn_mfma_f32_16x16x32_bf16(
                    af[mi], bfr[ni], acc[mi][ni], 0, 0, 0);
    }

    #pragma unroll
    for (int mi = 0; mi < 4; ++mi) {
        #pragma unroll
        for (int j = 0; j < 4; ++j) {
            const int r = bm * 256 + wr + mi * 16 + fq * 4 + j;
            #pragma unroll
            for (int ni = 0; ni < 4; ++ni) {
                const int c = bn * 128 + wc + ni * 16 + fr;
                float v = acc[mi][ni][j];
                if (BIAS) v += bias[c];
                __builtin_nontemporal_store(v, &Cf[(size_t)r * N + c]);
            }
        }
    }
}

// ---------------------------------------------------------------------------
// MFMA causal flash attention (R13, unchanged): load-balanced qt mapping —
// co-resident pair (L, L+256) does complementary x / 31-x tiles = 33/CU.
// ---------------------------------------------------------------------------
__global__ __launch_bounds__(256) void attn_kernel(
    const u16* __restrict__ qkv, u16* __restrict__ y)
{
    constexpr int LDK = 72;
    __shared__ u16 Kl[2][64 * LDK];
    __shared__ u16 Vt[2][64 * LDK];

    const int tid = threadIdx.x;
    const int bh = blockIdx.y;
    const int qt = (bh < 8) ? (int)blockIdx.x
                            : (int)gridDim.x - 1 - (int)blockIdx.x;
    const int b = bh >> 2, h = bh & 3;
    const int w = tid >> 6, lane = tid & 63;
    const int fr = lane & 15, fq = lane >> 4;
    const size_t rowbase = (size_t)b * TBLK;
    const int qoff = h * HSZ, koff = EMB + h * HSZ, voff = 2 * EMB + h * HSZ;
    const int qg = qt * 64 + w * 16 + fr;

    bf16x8v qf[2];
    #pragma unroll
    for (int ks = 0; ks < 2; ++ks)
        qf[ks] = *(const bf16x8v*)&qkv[(rowbase + qg) * QKVD + qoff + ks * 32 + fq * 8];

    f32x4 yac[4];
    #pragma unroll
    for (int mi = 0; mi < 4; ++mi) yac[mi] = f32x4{0.f, 0.f, 0.f, 0.f};
    float m = -1e30f, l = 0.f;

    const int skv = tid >> 2, sc = (tid & 3) * 16;
    const u16* kbase = &qkv[(rowbase + skv) * QKVD + koff + sc];
    const u16* vbase = &qkv[(rowbase + skv) * QKVD + voff + sc];

    bf16x8v kr0 = *(const bf16x8v*)kbase;
    bf16x8v kr1 = *(const bf16x8v*)(kbase + 8);
    bf16x8v vr0 = *(const bf16x8v*)vbase;
    bf16x8v vr1 = *(const bf16x8v*)(vbase + 8);

    int buf = 0;
    for (int kv0 = 0; kv0 <= qt * 64; kv0 += 64, buf ^= 1) {
        {
            u16* Kw = &Kl[buf][skv * LDK + sc];
            *(bf16x8v*)Kw = kr0; *(bf16x8v*)(Kw + 8) = kr1;
            #pragma unroll
            for (int i = 0; i < 8; ++i) Vt[buf][(sc + i) * LDK + skv] = (u16)vr0[i];
            #pragma unroll
            for (int i = 0; i < 8; ++i) Vt[buf][(sc + 8 + i) * LDK + skv] = (u16)vr1[i];
        }
        __syncthreads();
        if (kv0 + 64 <= qt * 64) {
            const size_t off = (size_t)(kv0 + 64) * QKVD;
            kr0 = *(const bf16x8v*)(kbase + off);
            kr1 = *(const bf16x8v*)(kbase + off + 8);
            vr0 = *(const bf16x8v*)(vbase + off);
            vr1 = *(const bf16x8v*)(vbase + off + 8);
        }

        f32x4 st[4];
        __builtin_amdgcn_s_setprio(1);
        #pragma unroll
        for (int mb = 0; mb < 4; ++mb) {
            st[mb] = f32x4{0.f, 0.f, 0.f, 0.f};
            #pragma unroll
            for (int ks = 0; ks < 2; ++ks) {
                const bf16x8v kf = *(const bf16x8v*)
                    &Kl[buf][(mb * 16 + fr) * LDK + ks * 32 + fq * 8];
                st[mb] = __builtin_amdgcn_mfma_f32_16x16x32_bf16(
                    kf, qf[ks], st[mb], 0, 0, 0);
            }
        }
        __builtin_amdgcn_s_setprio(0);
        float p[4][4];
        float mloc = -1e30f;
        #pragma unroll
        for (int mb = 0; mb < 4; ++mb)
            #pragma unroll
            for (int j = 0; j < 4; ++j) {
                const int kvg = kv0 + mb * 16 + fq * 4 + j;
                const float s = (kvg <= qg) ? st[mb][j] * 0.0625f : -1e30f;
                p[mb][j] = s;
                mloc = fmaxf(mloc, s);
            }
        mloc = fmaxf(mloc, __shfl_xor(mloc, 16));
        mloc = fmaxf(mloc, __shfl_xor(mloc, 32));
        const float mnew = fmaxf(m, mloc);
        const float alpha = __expf(m - mnew);
        float rsum = 0.f;
        #pragma unroll
        for (int mb = 0; mb < 4; ++mb)
            #pragma unroll
            for (int j = 0; j < 4; ++j) {
                p[mb][j] = __expf(p[mb][j] - mnew);
                rsum += p[mb][j];
            }
        rsum += __shfl_xor(rsum, 16);
        rsum += __shfl_xor(rsum, 32);
        l = l * alpha + rsum;
        m = mnew;
        #pragma unroll
        for (int mi = 0; mi < 4; ++mi) yac[mi] *= alpha;

        u32 pk[4][2];
        #pragma unroll
        for (int mb = 0; mb < 4; ++mb) {
            pk[mb][0] = pack2(p[mb][0], p[mb][1]);
            pk[mb][1] = pack2(p[mb][2], p[mb][3]);
        }
        #pragma unroll
        for (int ksv = 0; ksv < 2; ++ksv) {
            union { u32 u[4]; bf16x8v v; } pf;
            #pragma unroll
            for (int t = 0; t < 4; ++t) {
                const int srcl = ((fq & 1) * 2 + (t >> 1)) * 16 + fr;
                const u32 lo = __shfl(pk[ksv * 2 + 0][t & 1], srcl);
                const u32 hi = __shfl(pk[ksv * 2 + 1][t & 1], srcl);
                pf.u[t] = (fq >> 1) ? hi : lo;
            }
            __builtin_amdgcn_s_setprio(1);
            #pragma unroll
            for (int mi = 0; mi < 4; ++mi) {
                const bf16x8v vf = *(const bf16x8v*)
                    &Vt[buf][(mi * 16 + fr) * LDK + ksv * 32 + fq * 8];
                yac[mi] = __builtin_amdgcn_mfma_f32_16x16x32_bf16(
                    vf, pf.v, yac[mi], 0, 0, 0);
            }
            __builtin_amdgcn_s_setprio(0);
        }
    }

    const float inv = 1.f / l;
    #pragma unroll
    for (int mi = 0; mi < 4; ++mi) {
        ushort4 o;
        o.x = f2bf(yac[mi][0] * inv);
        o.y = f2bf(yac[mi][1] * inv);
        o.z = f2bf(yac[mi][2] * inv);
        o.w = f2bf(yac[mi][3] * inv);
        *(ushort4*)&y[(rowbase + qg) * EMB + h * HSZ + mi * 16 + fq * 4] = o;
    }
}

// ---------------------------------------------------------------------------
extern "C" void kernel_launch(void* const* d_in, const int* in_sizes, int n_in,
                              void* d_out, int out_size, void* d_ws, size_t ws_size,
                              hipStream_t stream) {
    const int*   idx   = (const int*)  d_in[0];
    const float* tok   = (const float*)d_in[1];
    const float* pos   = (const float*)d_in[2];
    const float* Wq    = (const float*)d_in[3];
    const float* Wk    = (const float*)d_in[4];
    const float* Wv    = (const float*)d_in[5];
    const float* Wproj = (const float*)d_in[6];
    const float* bproj = (const float*)d_in[7];
    const float* ln1g  = (const float*)d_in[8];
    const float* ln1b  = (const float*)d_in[9];
    const float* W1    = (const float*)d_in[10];
    const float* b1    = (const float*)d_in[11];
    const float* W2    = (const float*)d_in[12];
    const float* b2    = (const float*)d_in[13];
    const float* ln2g  = (const float*)d_in[14];
    const float* ln2b  = (const float*)d_in[15];
    const float* Wlm   = (const float*)d_in[16];
    const float* blm   = (const float*)d_in[17];
    float* out = (float*)d_out;

    float* x    = (float*)d_ws;
    u16*   hb   = (u16*)(x + (size_t)BT * EMB);
    u16*   qkvb = hb + (size_t)BT * EMB;
    u16*   yb   = qkvb + (size_t)BT * QKVD;
    u16*   hid  = qkvb;  // aliases qkv+yb (dead when MLP runs)
    u16*   Wqkvt  = yb + (size_t)BT * EMB;
    u16*   Wprojt = Wqkvt  + (size_t)NLAYER * QKVD * EMB;
    u16*   W1t    = Wprojt + (size_t)NLAYER * EMB * EMB;
    u16*   W2t    = W1t    + (size_t)NLAYER * EMB * 4 * EMB;
    u16*   Wlmt   = W2t    + (size_t)NLAYER * 4 * EMB * EMB;

    transpose_all<<<2304 + (VOCAB/32)*8, dim3(32, 8), 0, stream>>>(
        Wq, Wk, Wv, Wproj, W1, W2, Wlm, Wqkvt, Wprojt, W1t, W2t, Wlmt);

    embed_ln_kernel<<<BT/4, 256, 0, stream>>>(idx, tok, pos, ln1g, ln1b, x, hb);

    for (int l = 0; l < NLAYER; ++l) {
        mgemm64<0,0,0,1><<<dim3(BT/64, QKVD/64), 256, 0, stream>>>(
            hb, Wqkvt + (size_t)l*QKVD*EMB, nullptr, nullptr, qkvb, BT, QKVD, EMB);
        attn_kernel<<<dim3(TBLK/64, BATCH*NHEAD), 256, 0, stream>>>(qkvb, yb);
        mgemm64<1,1,0,0><<<dim3(BT/64, EMB/64), 256, 0, stream>>>(
            yb, Wprojt + (size_t)l*EMB*EMB, bproj + l*EMB, x, x, BT, EMB, EMB);
        ln_kernel<<<BT/4, 256, 0, stream>>>(x, ln2g + l*EMB, ln2b + l*EMB, hb);
        mgemm64<1,0,1,1><<<dim3(BT/64, 4*EMB/64), 256, 0, stream>>>(
            hb, W1t + (size_t)l*EMB*4*EMB, b1 + l*4*EMB, nullptr, hid, BT, 4*EMB, EMB);
        if (l < NLAYER - 1) {
            mgemm64<1,1,0,0><<<dim3(BT/64, EMB/64), 256, 0, stream>>>(
                hid, W2t + (size_t)l*4*EMB*EMB, b2 + l*EMB, x, x, BT, EMB, 4*EMB);
            ln_kernel<<<BT/4, 256, 0, stream>>>(
                x, ln1g + (l+1)*EMB, ln1b + (l+1)*EMB, hb);
        } else {
            mgemm64<1,1,0,1><<<dim3(BT/64, EMB/64), 256, 0, stream>>>(
                hid, W2t + (size_t)l*4*EMB*EMB, b2 + l*EMB, x, hb, BT, EMB, 4*EMB);
        }
    }

    mgemm_m256<1><<<dim3(BT/256, VOCAB/128), 512, 0, stream>>>(
        hb, Wlmt, blm, out, VOCAB, EMB);
}